// Round 13
// baseline (283.309 us; speedup 1.0000x reference)
//
#include <hip/hip_runtime.h>

static constexpr float BN_EPS = 1e-5f;
#define ELLW 64
#define STATB 512   // k_bnstats grid
#define BSHIFT 4    // 16 dsts per bucket
#define BCAP 320    // records per bucket (mean 256 at E/n=16)

typedef short short8 __attribute__((ext_vector_type(8)));
typedef float f32x4 __attribute__((ext_vector_type(4)));
union BF8 { short8 v; unsigned u[4]; uint4 q; };

__device__ __forceinline__ unsigned rne_bf16(float f) {
    unsigned u = __float_as_uint(f);
    u += 0x7fffu + ((u >> 16) & 1u);
    return u >> 16;
}
__device__ __forceinline__ float bflo(unsigned u) { return __uint_as_float(u << 16); }
__device__ __forceinline__ float bfhi(unsigned u) { return __uint_as_float(u & 0xffff0000u); }

// Detect whether edge_index is int64 (high words all zero) or int32.
__global__ __launch_bounds__(256) void k_detect_i64(const unsigned* __restrict__ ei,
                                                    int* __restrict__ flag) {
    if (blockIdx.x == 0 && threadIdx.x == 0) {
        int allz = 1;
        for (int i = 0; i < 256; ++i) {
            if (ei[2 * i + 1] != 0u) { allz = 0; break; }
        }
        *flag = allz;
    }
}

// Phase A: bucket edges by dst>>BSHIFT into append buffers (4B packed records).
// Sequential per-bucket appends -> L2 lines fill before eviction (low write amp).
// Bucket overflow falls back to direct ELL store (rare, per-edge).
__global__ __launch_bounds__(256) void k_bucket(const void* __restrict__ eidx, int E,
                                                const int* __restrict__ flag,
                                                int* __restrict__ bcnt,
                                                int* __restrict__ bbuf,
                                                int* __restrict__ deg,
                                                int* __restrict__ rec,
                                                int2* __restrict__ ovf,
                                                int* __restrict__ ovf_cnt, int ovf_cap) {
    const int base = blockIdx.x * 1024 + threadIdx.x;
    const bool is64 = (*flag != 0);
    int s[4], d[4];
    bool ok[4];
#pragma unroll
    for (int j = 0; j < 4; ++j) {
        int e = base + j * 256;
        ok[j] = e < E;
        if (ok[j]) {
            if (is64) {
                s[j] = (int)((const long long*)eidx)[e];
                d[j] = (int)((const long long*)eidx)[E + e];
            } else {
                s[j] = ((const int*)eidx)[e];
                d[j] = ((const int*)eidx)[E + e];
            }
        }
    }
    int pos[4];
#pragma unroll
    for (int j = 0; j < 4; ++j)
        if (ok[j]) pos[j] = atomicAdd(&bcnt[d[j] >> BSHIFT], 1);
#pragma unroll
    for (int j = 0; j < 4; ++j) {
        if (!ok[j]) continue;
        if (pos[j] < BCAP) {
            bbuf[(size_t)(d[j] >> BSHIFT) * BCAP + pos[j]] =
                (s[j] << BSHIFT) | (d[j] & ((1 << BSHIFT) - 1));
        } else {
            // rare: direct path (counts deg + places into ELL like old k_ell)
            int p2 = atomicAdd(&deg[d[j]], 1);
            if (p2 < ELLW) {
                rec[(size_t)d[j] * ELLW + p2] = s[j];
            } else {
                int o = atomicAdd(ovf_cnt, 1);
                if (o < ovf_cap) ovf[o] = make_int2(s[j], d[j]);
            }
        }
    }
}

// Phase B: one block per bucket; replay records into the bucket's 16 ELL rows
// (4KB working set -> each ELL line written back once).
__global__ __launch_bounds__(256) void k_fill(const int* __restrict__ bcnt,
                                              const int* __restrict__ bbuf,
                                              int* __restrict__ deg,
                                              int* __restrict__ rec,
                                              int2* __restrict__ ovf,
                                              int* __restrict__ ovf_cnt, int ovf_cap) {
    const int b = blockIdx.x;
    const int d0 = b << BSHIFT;
    int m = bcnt[b];
    if (m > BCAP) m = BCAP;
    for (int i = threadIdx.x; i < m; i += 256) {
        unsigned r = (unsigned)bbuf[(size_t)b * BCAP + i];
        int s = (int)(r >> BSHIFT);
        int d = d0 | (int)(r & ((1u << BSHIFT) - 1u));
        int pos = atomicAdd(&deg[d], 1);
        if (pos < ELLW) {
            rec[(size_t)d * ELLW + pos] = s;
        } else {
            int o = atomicAdd(ovf_cnt, 1);
            if (o < ovf_cap) ovf[o] = make_int2(s, d);
        }
    }
}

// MFMA bf16x3 split-precision GEMM: Y[n,128] = act(X)[n,128] @ W[128,128].
// act = relu(x*scale+shift) if scale != nullptr. Output bf16 (Yb) / f32 (Yf).
__global__ __launch_bounds__(256) void k_gemm_mfma(const float* __restrict__ X,
                                                   const float* __restrict__ W,
                                                   int n,
                                                   const float* __restrict__ scale,
                                                   const float* __restrict__ shift,
                                                   unsigned short* __restrict__ Yb,
                                                   float* __restrict__ Yf) {
    __shared__ unsigned short Xh[64][136];
    __shared__ unsigned short Xl[64][136];
    const int tid = threadIdx.x;
    const int lane = tid & 63;
    const int w = tid >> 6;
    const int row0 = blockIdx.x * 64;
    const int kb = (lane >> 4) * 8;
    const int cl16 = lane & 15;

    BF8 Bh[4][2], Bl[4][2];
#pragma unroll
    for (int ks = 0; ks < 4; ++ks) {
#pragma unroll
        for (int nn = 0; nn < 2; ++nn) {
            const float* wp = W + (size_t)(ks * 32 + kb) * 128 + w * 32 + nn * 16 + cl16;
            unsigned uh[8], ul[8];
#pragma unroll
            for (int j = 0; j < 8; ++j) {
                float v = wp[(size_t)j * 128];
                unsigned h = rne_bf16(v);
                unsigned l = rne_bf16(v - __uint_as_float(h << 16));
                uh[j] = h; ul[j] = l;
            }
#pragma unroll
            for (int t = 0; t < 4; ++t) {
                Bh[ks][nn].u[t] = uh[2 * t] | (uh[2 * t + 1] << 16);
                Bl[ks][nn].u[t] = ul[2 * t] | (ul[2 * t + 1] << 16);
            }
        }
    }

    for (int i = tid; i < 64 * 32; i += 256) {
        int r = i >> 5, c = i & 31;
        int gr = row0 + r;
        float4 v = (gr < n) ? ((const float4*)X)[(size_t)gr * 32 + c]
                            : float4{0.f, 0.f, 0.f, 0.f};
        if (scale) {
            float4 sc = ((const float4*)scale)[c];
            float4 sh = ((const float4*)shift)[c];
            v.x = fmaxf(fmaf(v.x, sc.x, sh.x), 0.f);
            v.y = fmaxf(fmaf(v.y, sc.y, sh.y), 0.f);
            v.z = fmaxf(fmaf(v.z, sc.z, sh.z), 0.f);
            v.w = fmaxf(fmaf(v.w, sc.w, sh.w), 0.f);
        }
#pragma unroll
        for (int j = 0; j < 4; ++j) {
            float f = (&v.x)[j];
            unsigned h = rne_bf16(f);
            unsigned l = rne_bf16(f - __uint_as_float(h << 16));
            Xh[r][c * 4 + j] = (unsigned short)h;
            Xl[r][c * 4 + j] = (unsigned short)l;
        }
    }
    __syncthreads();

    f32x4 acc[4][2];
#pragma unroll
    for (int m = 0; m < 4; ++m)
#pragma unroll
        for (int nn = 0; nn < 2; ++nn) acc[m][nn] = f32x4{0.f, 0.f, 0.f, 0.f};
#pragma unroll
    for (int ks = 0; ks < 4; ++ks) {
        BF8 Ah[4], Al[4];
#pragma unroll
        for (int m = 0; m < 4; ++m) {
            const int r = m * 16 + cl16;
            const int cc = ks * 32 + kb;
            Ah[m].q = *(const uint4*)&Xh[r][cc];
            Al[m].q = *(const uint4*)&Xl[r][cc];
        }
#pragma unroll
        for (int m = 0; m < 4; ++m) {
#pragma unroll
            for (int nn = 0; nn < 2; ++nn) {
                acc[m][nn] = __builtin_amdgcn_mfma_f32_16x16x32_bf16(Ah[m].v, Bh[ks][nn].v, acc[m][nn], 0, 0, 0);
                acc[m][nn] = __builtin_amdgcn_mfma_f32_16x16x32_bf16(Ah[m].v, Bl[ks][nn].v, acc[m][nn], 0, 0, 0);
                acc[m][nn] = __builtin_amdgcn_mfma_f32_16x16x32_bf16(Al[m].v, Bh[ks][nn].v, acc[m][nn], 0, 0, 0);
            }
        }
    }

    const int rb2 = (lane >> 4) * 4;
#pragma unroll
    for (int m = 0; m < 4; ++m) {
#pragma unroll
        for (int nn = 0; nn < 2; ++nn) {
            const int col = w * 32 + nn * 16 + cl16;
#pragma unroll
            for (int r = 0; r < 4; ++r) {
                int gr = row0 + m * 16 + rb2 + r;
                if (gr < n) {
                    float val = acc[m][nn][r];
                    if (Yb) Yb[(size_t)gr * 128 + col] = (unsigned short)rne_bf16(val);
                    if (Yf) Yf[(size_t)gr * 128 + col] = val;
                }
            }
        }
    }
}

// f32 GEMM (fallback path only).
__global__ __launch_bounds__(256) void k_gemm_f32(const float* __restrict__ X,
                                                  const float* __restrict__ W,
                                                  int n,
                                                  float* __restrict__ Yf) {
    __shared__ float Ws[128 * 128];
    __shared__ float Xs[32 * 128];
    const int tid = threadIdx.x;
    for (int i = tid; i < 128 * 32; i += 256)
        ((float4*)Ws)[i] = ((const float4*)W)[i];
    const int row0 = blockIdx.x * 32;
    for (int i = tid; i < 32 * 32; i += 256) {
        int r = i >> 5, c = i & 31;
        int gr = row0 + r;
        float4 v = (gr < n) ? ((const float4*)X)[(size_t)gr * 32 + c]
                            : float4{0.f, 0.f, 0.f, 0.f};
        ((float4*)Xs)[i] = v;
    }
    __syncthreads();
    const int c4 = (tid & 31) * 4;
    const int rb = tid >> 5;
    float4 acc[4];
#pragma unroll
    for (int j = 0; j < 4; ++j) acc[j] = float4{0.f, 0.f, 0.f, 0.f};
    for (int k = 0; k < 128; ++k) {
        float4 w = *(const float4*)&Ws[k * 128 + c4];
#pragma unroll
        for (int j = 0; j < 4; ++j) {
            float xv = Xs[(rb + 8 * j) * 128 + k];
            acc[j].x = fmaf(xv, w.x, acc[j].x);
            acc[j].y = fmaf(xv, w.y, acc[j].y);
            acc[j].z = fmaf(xv, w.z, acc[j].z);
            acc[j].w = fmaf(xv, w.w, acc[j].w);
        }
    }
#pragma unroll
    for (int j = 0; j < 4; ++j) {
        int r = row0 + rb + 8 * j;
        if (r < n) *(float4*)&Yf[(size_t)r * 128 + c4] = acc[j];
    }
}

// One wave per dst row (R10 structure, verbatim).
__global__ __launch_bounds__(256) void k_agg(const int* __restrict__ rec,
                                             const int* __restrict__ deg,
                                             const unsigned* __restrict__ Hb,
                                             const float* __restrict__ bias,
                                             float* __restrict__ B, int n) {
    const int d = blockIdx.x * 4 + (threadIdx.x >> 6);
    if (d >= n) return;
    const int lane = threadIdx.x & 63;
    const int cnt = __builtin_amdgcn_readfirstlane(deg[d]);
    const int cl = cnt < ELLW ? cnt : ELLW;
    const float dinv_d = rsqrtf((float)(cnt + 1));
    const float selfn = dinv_d * dinv_d;
    unsigned hu = Hb[(size_t)d * 64 + lane];
    float2 bb = ((const float2*)bias)[lane];
    float accx = fmaf(bflo(hu), selfn, bb.x);
    float accy = fmaf(bfhi(hu), selfn, bb.y);
    const int* row = rec + (size_t)d * ELLW;
    int e = 0;
    for (; e + 3 < cl; e += 4) {
        int4 ra = *(const int4*)&row[e];
        float n0 = rsqrtf((float)(deg[ra.x] + 1)) * dinv_d;
        float n1 = rsqrtf((float)(deg[ra.y] + 1)) * dinv_d;
        float n2 = rsqrtf((float)(deg[ra.z] + 1)) * dinv_d;
        float n3 = rsqrtf((float)(deg[ra.w] + 1)) * dinv_d;
        unsigned u0 = Hb[(size_t)ra.x * 64 + lane];
        unsigned u1 = Hb[(size_t)ra.y * 64 + lane];
        unsigned u2 = Hb[(size_t)ra.z * 64 + lane];
        unsigned u3 = Hb[(size_t)ra.w * 64 + lane];
        accx = fmaf(bflo(u0), n0, accx); accy = fmaf(bfhi(u0), n0, accy);
        accx = fmaf(bflo(u1), n1, accx); accy = fmaf(bfhi(u1), n1, accy);
        accx = fmaf(bflo(u2), n2, accx); accy = fmaf(bfhi(u2), n2, accy);
        accx = fmaf(bflo(u3), n3, accx); accy = fmaf(bfhi(u3), n3, accy);
    }
    for (; e < cl; ++e) {
        int r = row[e];
        float n0 = rsqrtf((float)(deg[r] + 1)) * dinv_d;
        unsigned u0 = Hb[(size_t)r * 64 + lane];
        accx = fmaf(bflo(u0), n0, accx); accy = fmaf(bfhi(u0), n0, accy);
    }
    ((float2*)(B + (size_t)d * 128))[lane] = make_float2(accx, accy);
}

// Replay overflow edges (normally zero) with f32 atomics.
__global__ __launch_bounds__(256) void k_ovf(const int2* __restrict__ ovf,
                                             const int* __restrict__ ovf_cnt,
                                             const int* __restrict__ deg,
                                             const unsigned* __restrict__ Hb,
                                             float* __restrict__ B, int ovf_cap) {
    int m = *ovf_cnt;
    if (m > ovf_cap) m = ovf_cap;
    const int lane = threadIdx.x & 63;
    for (int i = blockIdx.x * 4 + (threadIdx.x >> 6); i < m; i += gridDim.x * 4) {
        int2 sd = ovf[i];
        float nrm = rsqrtf((float)(deg[sd.x] + 1)) * rsqrtf((float)(deg[sd.y] + 1));
        unsigned u = Hb[(size_t)sd.x * 64 + lane];
        atomicAdd(&B[(size_t)sd.y * 128 + 2 * lane], bflo(u) * nrm);
        atomicAdd(&B[(size_t)sd.y * 128 + 2 * lane + 1], bfhi(u) * nrm);
    }
}

// Per-block column partials (non-atomic); grid = STATB blocks.
__global__ __launch_bounds__(256) void k_bnstats(const float* __restrict__ B, int n,
                                                 float* __restrict__ partials) {
    __shared__ float rs[256], rss[256];
    int col = threadIdx.x & 127;
    int rg = threadIdx.x >> 7;
    float s = 0.f, ss = 0.f;
    for (int r = blockIdx.x * 2 + rg; r < n; r += gridDim.x * 2) {
        float v = B[(size_t)r * 128 + col];
        s += v;
        ss = fmaf(v, v, ss);
    }
    rs[threadIdx.x] = s;
    rss[threadIdx.x] = ss;
    __syncthreads();
    if (threadIdx.x < 128) {
        partials[blockIdx.x * 256 + threadIdx.x] = rs[threadIdx.x] + rs[threadIdx.x + 128];
        partials[blockIdx.x * 256 + 128 + threadIdx.x] = rss[threadIdx.x] + rss[threadIdx.x + 128];
    }
}

// Parallel reduce of STATB partial blocks -> folded BN affine (scale, shift).
__global__ __launch_bounds__(1024) void k_bnfold(const float* __restrict__ partials,
                                                 const float* __restrict__ gamma,
                                                 const float* __restrict__ beta,
                                                 float invn, int nblk,
                                                 float* __restrict__ scale,
                                                 float* __restrict__ shift) {
    __shared__ float ls[8][128], lq[8][128];
    const int col = threadIdx.x & 127;
    const int grp = threadIdx.x >> 7;  // 0..7
    float s = 0.f, ss = 0.f;
#pragma unroll 4
    for (int b = grp; b < nblk; b += 8) {
        s += partials[b * 256 + col];
        ss += partials[b * 256 + 128 + col];
    }
    ls[grp][col] = s;
    lq[grp][col] = ss;
    __syncthreads();
    if (threadIdx.x < 128) {
        int c = threadIdx.x;
        float st = 0.f, sq = 0.f;
#pragma unroll
        for (int g = 0; g < 8; ++g) { st += ls[g][c]; sq += lq[g][c]; }
        float m = st * invn;
        float var = fmaf(-m, m, sq * invn);
        float sc = rsqrtf(var + BN_EPS) * gamma[c];
        scale[c] = sc;
        shift[c] = fmaf(-m, sc, beta[c]);
    }
}

// out = relu(x*scale + shift)
__global__ __launch_bounds__(256) void k_bnapply(const float* __restrict__ Bin,
                                                 float* __restrict__ out,
                                                 const float* __restrict__ scale,
                                                 const float* __restrict__ shift,
                                                 int n) {
    int idx = blockIdx.x * 256 + threadIdx.x;
    if (idx >= n * 32) return;
    int c4 = idx & 31;
    float4 x = ((const float4*)Bin)[idx];
    float4 sc = ((const float4*)scale)[c4];
    float4 sh = ((const float4*)shift)[c4];
    float4 o;
    o.x = fmaxf(fmaf(x.x, sc.x, sh.x), 0.f);
    o.y = fmaxf(fmaf(x.y, sc.y, sh.y), 0.f);
    o.z = fmaxf(fmaf(x.z, sc.z, sh.z), 0.f);
    o.w = fmaxf(fmaf(x.w, sc.w, sh.w), 0.f);
    ((float4*)out)[idx] = o;
}

// ---- fallback (atomic) path kernels ----
__global__ __launch_bounds__(256) void k_init_deg(int* __restrict__ deg, int n) {
    int i = blockIdx.x * 256 + threadIdx.x;
    if (i < n) deg[i] = 1;
}

__global__ __launch_bounds__(256) void k_count_deg(const void* __restrict__ eidx, int E,
                                                   const int* __restrict__ flag,
                                                   int* __restrict__ deg) {
    int e = blockIdx.x * 256 + threadIdx.x;
    if (e >= E) return;
    int d;
    if (*flag) d = (int)((const long long*)eidx)[E + e];
    else       d = ((const int*)eidx)[E + e];
    atomicAdd(&deg[d], 1);
}

__global__ __launch_bounds__(256) void k_dinv(const int* __restrict__ deg,
                                              float* __restrict__ dinv, int n) {
    int i = blockIdx.x * 256 + threadIdx.x;
    if (i < n) dinv[i] = rsqrtf((float)deg[i]);
}

__global__ __launch_bounds__(256) void k_selfloop(const float* __restrict__ H,
                                                  const float* __restrict__ dinv,
                                                  const float* __restrict__ bias,
                                                  float* __restrict__ B, int n) {
    int idx = blockIdx.x * 256 + threadIdx.x;
    if (idx >= n * 32) return;
    int r = idx >> 5, c = idx & 31;
    float s = dinv[r];
    s *= s;
    float4 h = ((const float4*)H)[idx];
    float4 bb = ((const float4*)bias)[c];
    float4 o{fmaf(h.x, s, bb.x), fmaf(h.y, s, bb.y),
             fmaf(h.z, s, bb.z), fmaf(h.w, s, bb.w)};
    ((float4*)B)[idx] = o;
}

__global__ __launch_bounds__(256) void k_edge(const void* __restrict__ eidx, int E,
                                              const int* __restrict__ flag,
                                              const float* __restrict__ dinv,
                                              const float* __restrict__ H,
                                              float* __restrict__ B) {
    int e = blockIdx.x * 8 + (threadIdx.x >> 5);
    if (e >= E) return;
    int lane = threadIdx.x & 31;
    int s, d;
    if (*flag) {
        s = (int)((const long long*)eidx)[e];
        d = (int)((const long long*)eidx)[E + e];
    } else {
        s = ((const int*)eidx)[e];
        d = ((const int*)eidx)[E + e];
    }
    float nrm = dinv[s] * dinv[d];
    float4 h = ((const float4*)(H + (size_t)s * 128))[lane];
    float* out = B + (size_t)d * 128 + lane * 4;
    atomicAdd(out + 0, h.x * nrm);
    atomicAdd(out + 1, h.y * nrm);
    atomicAdd(out + 2, h.z * nrm);
    atomicAdd(out + 3, h.w * nrm);
}

static inline char* align256(char* p) {
    return (char*)(((uintptr_t)p + 255) & ~(uintptr_t)255);
}

extern "C" void kernel_launch(void* const* d_in, const int* in_sizes, int n_in,
                              void* d_out, int out_size, void* d_ws, size_t ws_size,
                              hipStream_t stream) {
    const float* x   = (const float*)d_in[0];
    const void*  ei  = d_in[1];
    const float* W1  = (const float*)d_in[2];
    const float* b1  = (const float*)d_in[3];
    const float* g1  = (const float*)d_in[4];
    const float* be1 = (const float*)d_in[5];
    const float* W2  = (const float*)d_in[6];
    const float* b2  = (const float*)d_in[7];
    const float* g2  = (const float*)d_in[8];
    const float* be2 = (const float*)d_in[9];

    const int n = in_sizes[0] / 128;
    const int E = in_sizes[1] / 2;
    const float invn = 1.0f / (float)n;
    float* out = (float*)d_out;

    const int nb_n   = (n + 255) / 256;
    const int nb_e   = (E + 255) / 256;
    const int nb_e4  = (E + 1023) / 1024;   // k_bucket: 4 edges/thread
    const int nb_el  = (n * 32 + 255) / 256;
    const int nb_gm  = (n + 63) / 64;
    const int nb_gf  = (n + 31) / 32;
    const int nb_edge = (E + 7) / 8;
    const int nb_agg = (n + 3) / 4;
    const int nbkt   = (n + (1 << BSHIFT) - 1) >> BSHIFT;  // buckets

    // ---- main (ELL) layout ----
    char* p = (char*)d_ws;
    float* B = (float*)p;                      p += (size_t)n * 128 * 4;
    unsigned short* Ab = (unsigned short*)p;   p += (size_t)n * 128 * 2;
    p = align256(p);
    int* rec = (int*)p;                        p += (size_t)n * ELLW * 4;
    int2* ovf = (int2*)p;                      p += (size_t)E * 8;
    int* bbuf = (int*)p;                       p += (size_t)nbkt * BCAP * 4;
    int* deg = (int*)p;                        p += (size_t)n * 4;
    int* ovf_cnt = (int*)p;                    p += 4;
    int* bcnt = (int*)p;                       p += (size_t)nbkt * 4;  // zeroed with deg
    p = align256(p);
    float* partials = (float*)p;               p += (size_t)STATB * 256 * 4;
    float* scale = (float*)p;                  p += 128 * 4;
    float* shift = (float*)p;                  p += 128 * 4;
    int* flag = (int*)p;                       p += 16;
    const bool ell_ok = (size_t)(p - (char*)d_ws) <= ws_size;

    if (ell_ok) {
        k_detect_i64<<<1, 256, 0, stream>>>((const unsigned*)ei, flag);
        hipMemsetAsync(deg, 0, (size_t)n * 4 + 4 + (size_t)nbkt * 4, stream);  // deg+ovf_cnt+bcnt
        k_bucket<<<nb_e4, 256, 0, stream>>>(ei, E, flag, bcnt, bbuf, deg, rec, ovf, ovf_cnt, E);
        k_fill<<<nbkt, 256, 0, stream>>>(bcnt, bbuf, deg, rec, ovf, ovf_cnt, E);

        // ---- layer 1 ----
        k_gemm_mfma<<<nb_gm, 256, 0, stream>>>(x, W1, n, nullptr, nullptr, Ab, nullptr);
        k_agg<<<nb_agg, 256, 0, stream>>>(rec, deg, (const unsigned*)Ab, b1, B, n);
        k_ovf<<<64, 256, 0, stream>>>(ovf, ovf_cnt, deg, (const unsigned*)Ab, B, E);
        k_bnstats<<<STATB, 256, 0, stream>>>(B, n, partials);
        k_bnfold<<<1, 1024, 0, stream>>>(partials, g1, be1, invn, STATB, scale, shift);

        // ---- layer 2 (BN1+ReLU folded into GEMM staging) ----
        k_gemm_mfma<<<nb_gm, 256, 0, stream>>>(B, W2, n, scale, shift, Ab, nullptr);
        k_agg<<<nb_agg, 256, 0, stream>>>(rec, deg, (const unsigned*)Ab, b2, B, n);
        k_ovf<<<64, 256, 0, stream>>>(ovf, ovf_cnt, deg, (const unsigned*)Ab, B, E);
        k_bnstats<<<STATB, 256, 0, stream>>>(B, n, partials);
        k_bnfold<<<1, 1024, 0, stream>>>(partials, g2, be2, invn, STATB, scale, shift);
        k_bnapply<<<nb_el, 256, 0, stream>>>(B, out, scale, shift, n);
    } else {
        // ---- fallback: atomic scatter path (f32 H) ----
        char* q = (char*)d_ws;
        float* A = (float*)q;        q += (size_t)n * 128 * 4;
        float* Bf = (float*)q;       q += (size_t)n * 128 * 4;
        int* degf = (int*)q;         q += (size_t)n * 4;
        float* dinv = (float*)q;     q += (size_t)n * 4;
        q = align256(q);
        float* part = (float*)q;     q += (size_t)STATB * 256 * 4;
        float* sc = (float*)q;       q += 128 * 4;
        float* sh = (float*)q;       q += 128 * 4;
        int* flg = (int*)q;          q += 16;

        k_detect_i64<<<1, 256, 0, stream>>>((const unsigned*)ei, flg);
        k_init_deg<<<nb_n, 256, 0, stream>>>(degf, n);
        k_count_deg<<<nb_e, 256, 0, stream>>>(ei, E, flg, degf);
        k_dinv<<<nb_n, 256, 0, stream>>>(degf, dinv, n);

        k_gemm_f32<<<nb_gf, 256, 0, stream>>>(x, W1, n, A);
        k_selfloop<<<nb_el, 256, 0, stream>>>(A, dinv, b1, Bf, n);
        k_edge<<<nb_edge, 256, 0, stream>>>(ei, E, flg, dinv, A, Bf);
        k_bnstats<<<STATB, 256, 0, stream>>>(Bf, n, part);
        k_bnfold<<<1, 1024, 0, stream>>>(part, g1, be1, invn, STATB, sc, sh);
        k_bnapply<<<nb_el, 256, 0, stream>>>(Bf, Bf, sc, sh, n);

        k_gemm_f32<<<nb_gf, 256, 0, stream>>>(Bf, W2, n, A);
        k_selfloop<<<nb_el, 256, 0, stream>>>(A, dinv, b2, Bf, n);
        k_edge<<<nb_edge, 256, 0, stream>>>(ei, E, flg, dinv, A, Bf);
        k_bnstats<<<STATB, 256, 0, stream>>>(Bf, n, part);
        k_bnfold<<<1, 1024, 0, stream>>>(part, g2, be2, invn, STATB, sc, sh);
        k_bnapply<<<nb_el, 256, 0, stream>>>(Bf, out, sc, sh, n);
    }
}

// Round 14
// 230.519 us; speedup vs baseline: 1.2290x; 1.2290x over previous
//
#include <hip/hip_runtime.h>

static constexpr float BN_EPS = 1e-5f;
#define ELLW 64
#define STATB 512   // k_bnstats grid

typedef short short8 __attribute__((ext_vector_type(8)));
typedef float f32x4 __attribute__((ext_vector_type(4)));
union BF8 { short8 v; unsigned u[4]; uint4 q; };

__device__ __forceinline__ unsigned rne_bf16(float f) {
    unsigned u = __float_as_uint(f);
    u += 0x7fffu + ((u >> 16) & 1u);
    return u >> 16;
}
__device__ __forceinline__ float bflo(unsigned u) { return __uint_as_float(u << 16); }
__device__ __forceinline__ float bfhi(unsigned u) { return __uint_as_float(u & 0xffff0000u); }

// Detect whether edge_index is int64 (high words all zero) or int32.
__global__ __launch_bounds__(256) void k_detect_i64(const unsigned* __restrict__ ei,
                                                    int* __restrict__ flag) {
    if (blockIdx.x == 0 && threadIdx.x == 0) {
        int allz = 1;
        for (int i = 0; i < 256; ++i) {
            if (ei[2 * i + 1] != 0u) { allz = 0; break; }
        }
        *flag = allz;
    }
}

// One pass: count degree AND bin edges into fixed-width ELL rows.
// 4 edges per thread (strided) -> 4 independent atomic->store chains in flight.
// NOTE (R12 lesson): direct random scatter beats CSR-scatter and 2-phase
// bucketing on this chip; write-amp (~48MB) is the floor for this pattern.
__global__ __launch_bounds__(256) void k_ell(const void* __restrict__ eidx, int E,
                                             const int* __restrict__ flag,
                                             int* __restrict__ deg,
                                             int* __restrict__ rec,
                                             int2* __restrict__ ovf,
                                             int* __restrict__ ovf_cnt, int ovf_cap) {
    const int base = blockIdx.x * 1024 + threadIdx.x;
    const bool is64 = (*flag != 0);
    int s[4], d[4];
    bool ok[4];
#pragma unroll
    for (int j = 0; j < 4; ++j) {
        int e = base + j * 256;
        ok[j] = e < E;
        if (ok[j]) {
            if (is64) {
                s[j] = (int)((const long long*)eidx)[e];
                d[j] = (int)((const long long*)eidx)[E + e];
            } else {
                s[j] = ((const int*)eidx)[e];
                d[j] = ((const int*)eidx)[E + e];
            }
        }
    }
    int pos[4];
#pragma unroll
    for (int j = 0; j < 4; ++j)
        if (ok[j]) pos[j] = atomicAdd(&deg[d[j]], 1);
#pragma unroll
    for (int j = 0; j < 4; ++j) {
        if (!ok[j]) continue;
        if (pos[j] < ELLW) {
            rec[(size_t)d[j] * ELLW + pos[j]] = s[j];
        } else {
            int o = atomicAdd(ovf_cnt, 1);
            if (o < ovf_cap) ovf[o] = make_int2(s[j], d[j]);
        }
    }
}

// MFMA bf16x3 split-precision GEMM: Y[n,128] = act(X)[n,128] @ W[128,128].
// act = relu(x*scale+shift) if scale != nullptr. Output bf16 (Yb) / f32 (Yf).
__global__ __launch_bounds__(256) void k_gemm_mfma(const float* __restrict__ X,
                                                   const float* __restrict__ W,
                                                   int n,
                                                   const float* __restrict__ scale,
                                                   const float* __restrict__ shift,
                                                   unsigned short* __restrict__ Yb,
                                                   float* __restrict__ Yf) {
    __shared__ unsigned short Xh[64][136];
    __shared__ unsigned short Xl[64][136];
    const int tid = threadIdx.x;
    const int lane = tid & 63;
    const int w = tid >> 6;
    const int row0 = blockIdx.x * 64;
    const int kb = (lane >> 4) * 8;
    const int cl16 = lane & 15;

    BF8 Bh[4][2], Bl[4][2];
#pragma unroll
    for (int ks = 0; ks < 4; ++ks) {
#pragma unroll
        for (int nn = 0; nn < 2; ++nn) {
            const float* wp = W + (size_t)(ks * 32 + kb) * 128 + w * 32 + nn * 16 + cl16;
            unsigned uh[8], ul[8];
#pragma unroll
            for (int j = 0; j < 8; ++j) {
                float v = wp[(size_t)j * 128];
                unsigned h = rne_bf16(v);
                unsigned l = rne_bf16(v - __uint_as_float(h << 16));
                uh[j] = h; ul[j] = l;
            }
#pragma unroll
            for (int t = 0; t < 4; ++t) {
                Bh[ks][nn].u[t] = uh[2 * t] | (uh[2 * t + 1] << 16);
                Bl[ks][nn].u[t] = ul[2 * t] | (ul[2 * t + 1] << 16);
            }
        }
    }

    for (int i = tid; i < 64 * 32; i += 256) {
        int r = i >> 5, c = i & 31;
        int gr = row0 + r;
        float4 v = (gr < n) ? ((const float4*)X)[(size_t)gr * 32 + c]
                            : float4{0.f, 0.f, 0.f, 0.f};
        if (scale) {
            float4 sc = ((const float4*)scale)[c];
            float4 sh = ((const float4*)shift)[c];
            v.x = fmaxf(fmaf(v.x, sc.x, sh.x), 0.f);
            v.y = fmaxf(fmaf(v.y, sc.y, sh.y), 0.f);
            v.z = fmaxf(fmaf(v.z, sc.z, sh.z), 0.f);
            v.w = fmaxf(fmaf(v.w, sc.w, sh.w), 0.f);
        }
#pragma unroll
        for (int j = 0; j < 4; ++j) {
            float f = (&v.x)[j];
            unsigned h = rne_bf16(f);
            unsigned l = rne_bf16(f - __uint_as_float(h << 16));
            Xh[r][c * 4 + j] = (unsigned short)h;
            Xl[r][c * 4 + j] = (unsigned short)l;
        }
    }
    __syncthreads();

    f32x4 acc[4][2];
#pragma unroll
    for (int m = 0; m < 4; ++m)
#pragma unroll
        for (int nn = 0; nn < 2; ++nn) acc[m][nn] = f32x4{0.f, 0.f, 0.f, 0.f};
#pragma unroll
    for (int ks = 0; ks < 4; ++ks) {
        BF8 Ah[4], Al[4];
#pragma unroll
        for (int m = 0; m < 4; ++m) {
            const int r = m * 16 + cl16;
            const int cc = ks * 32 + kb;
            Ah[m].q = *(const uint4*)&Xh[r][cc];
            Al[m].q = *(const uint4*)&Xl[r][cc];
        }
#pragma unroll
        for (int m = 0; m < 4; ++m) {
#pragma unroll
            for (int nn = 0; nn < 2; ++nn) {
                acc[m][nn] = __builtin_amdgcn_mfma_f32_16x16x32_bf16(Ah[m].v, Bh[ks][nn].v, acc[m][nn], 0, 0, 0);
                acc[m][nn] = __builtin_amdgcn_mfma_f32_16x16x32_bf16(Ah[m].v, Bl[ks][nn].v, acc[m][nn], 0, 0, 0);
                acc[m][nn] = __builtin_amdgcn_mfma_f32_16x16x32_bf16(Al[m].v, Bh[ks][nn].v, acc[m][nn], 0, 0, 0);
            }
        }
    }

    const int rb2 = (lane >> 4) * 4;
#pragma unroll
    for (int m = 0; m < 4; ++m) {
#pragma unroll
        for (int nn = 0; nn < 2; ++nn) {
            const int col = w * 32 + nn * 16 + cl16;
#pragma unroll
            for (int r = 0; r < 4; ++r) {
                int gr = row0 + m * 16 + rb2 + r;
                if (gr < n) {
                    float val = acc[m][nn][r];
                    if (Yb) Yb[(size_t)gr * 128 + col] = (unsigned short)rne_bf16(val);
                    if (Yf) Yf[(size_t)gr * 128 + col] = val;
                }
            }
        }
    }
}

// f32 GEMM (fallback path only).
__global__ __launch_bounds__(256) void k_gemm_f32(const float* __restrict__ X,
                                                  const float* __restrict__ W,
                                                  int n,
                                                  float* __restrict__ Yf) {
    __shared__ float Ws[128 * 128];
    __shared__ float Xs[32 * 128];
    const int tid = threadIdx.x;
    for (int i = tid; i < 128 * 32; i += 256)
        ((float4*)Ws)[i] = ((const float4*)W)[i];
    const int row0 = blockIdx.x * 32;
    for (int i = tid; i < 32 * 32; i += 256) {
        int r = i >> 5, c = i & 31;
        int gr = row0 + r;
        float4 v = (gr < n) ? ((const float4*)X)[(size_t)gr * 32 + c]
                            : float4{0.f, 0.f, 0.f, 0.f};
        ((float4*)Xs)[i] = v;
    }
    __syncthreads();
    const int c4 = (tid & 31) * 4;
    const int rb = tid >> 5;
    float4 acc[4];
#pragma unroll
    for (int j = 0; j < 4; ++j) acc[j] = float4{0.f, 0.f, 0.f, 0.f};
    for (int k = 0; k < 128; ++k) {
        float4 w = *(const float4*)&Ws[k * 128 + c4];
#pragma unroll
        for (int j = 0; j < 4; ++j) {
            float xv = Xs[(rb + 8 * j) * 128 + k];
            acc[j].x = fmaf(xv, w.x, acc[j].x);
            acc[j].y = fmaf(xv, w.y, acc[j].y);
            acc[j].z = fmaf(xv, w.z, acc[j].z);
            acc[j].w = fmaf(xv, w.w, acc[j].w);
        }
    }
#pragma unroll
    for (int j = 0; j < 4; ++j) {
        int r = row0 + rb + 8 * j;
        if (r < n) *(float4*)&Yf[(size_t)r * 128 + c4] = acc[j];
    }
}

// One wave per dst row (R10 structure, verbatim).
__global__ __launch_bounds__(256) void k_agg(const int* __restrict__ rec,
                                             const int* __restrict__ deg,
                                             const unsigned* __restrict__ Hb,
                                             const float* __restrict__ bias,
                                             float* __restrict__ B, int n) {
    const int d = blockIdx.x * 4 + (threadIdx.x >> 6);
    if (d >= n) return;
    const int lane = threadIdx.x & 63;
    const int cnt = __builtin_amdgcn_readfirstlane(deg[d]);
    const int cl = cnt < ELLW ? cnt : ELLW;
    const float dinv_d = rsqrtf((float)(cnt + 1));
    const float selfn = dinv_d * dinv_d;
    unsigned hu = Hb[(size_t)d * 64 + lane];
    float2 bb = ((const float2*)bias)[lane];
    float accx = fmaf(bflo(hu), selfn, bb.x);
    float accy = fmaf(bfhi(hu), selfn, bb.y);
    const int* row = rec + (size_t)d * ELLW;
    int e = 0;
    for (; e + 3 < cl; e += 4) {
        int4 ra = *(const int4*)&row[e];
        float n0 = rsqrtf((float)(deg[ra.x] + 1)) * dinv_d;
        float n1 = rsqrtf((float)(deg[ra.y] + 1)) * dinv_d;
        float n2 = rsqrtf((float)(deg[ra.z] + 1)) * dinv_d;
        float n3 = rsqrtf((float)(deg[ra.w] + 1)) * dinv_d;
        unsigned u0 = Hb[(size_t)ra.x * 64 + lane];
        unsigned u1 = Hb[(size_t)ra.y * 64 + lane];
        unsigned u2 = Hb[(size_t)ra.z * 64 + lane];
        unsigned u3 = Hb[(size_t)ra.w * 64 + lane];
        accx = fmaf(bflo(u0), n0, accx); accy = fmaf(bfhi(u0), n0, accy);
        accx = fmaf(bflo(u1), n1, accx); accy = fmaf(bfhi(u1), n1, accy);
        accx = fmaf(bflo(u2), n2, accx); accy = fmaf(bfhi(u2), n2, accy);
        accx = fmaf(bflo(u3), n3, accx); accy = fmaf(bfhi(u3), n3, accy);
    }
    for (; e < cl; ++e) {
        int r = row[e];
        float n0 = rsqrtf((float)(deg[r] + 1)) * dinv_d;
        unsigned u0 = Hb[(size_t)r * 64 + lane];
        accx = fmaf(bflo(u0), n0, accx); accy = fmaf(bfhi(u0), n0, accy);
    }
    ((float2*)(B + (size_t)d * 128))[lane] = make_float2(accx, accy);
}

// Replay overflow edges (normally zero) with f32 atomics.
__global__ __launch_bounds__(256) void k_ovf(const int2* __restrict__ ovf,
                                             const int* __restrict__ ovf_cnt,
                                             const int* __restrict__ deg,
                                             const unsigned* __restrict__ Hb,
                                             float* __restrict__ B, int ovf_cap) {
    int m = *ovf_cnt;
    if (m > ovf_cap) m = ovf_cap;
    const int lane = threadIdx.x & 63;
    for (int i = blockIdx.x * 4 + (threadIdx.x >> 6); i < m; i += gridDim.x * 4) {
        int2 sd = ovf[i];
        float nrm = rsqrtf((float)(deg[sd.x] + 1)) * rsqrtf((float)(deg[sd.y] + 1));
        unsigned u = Hb[(size_t)sd.x * 64 + lane];
        atomicAdd(&B[(size_t)sd.y * 128 + 2 * lane], bflo(u) * nrm);
        atomicAdd(&B[(size_t)sd.y * 128 + 2 * lane + 1], bfhi(u) * nrm);
    }
}

// Per-block column partials (non-atomic); grid = STATB blocks.
__global__ __launch_bounds__(256) void k_bnstats(const float* __restrict__ B, int n,
                                                 float* __restrict__ partials) {
    __shared__ float rs[256], rss[256];
    int col = threadIdx.x & 127;
    int rg = threadIdx.x >> 7;
    float s = 0.f, ss = 0.f;
    for (int r = blockIdx.x * 2 + rg; r < n; r += gridDim.x * 2) {
        float v = B[(size_t)r * 128 + col];
        s += v;
        ss = fmaf(v, v, ss);
    }
    rs[threadIdx.x] = s;
    rss[threadIdx.x] = ss;
    __syncthreads();
    if (threadIdx.x < 128) {
        partials[blockIdx.x * 256 + threadIdx.x] = rs[threadIdx.x] + rs[threadIdx.x + 128];
        partials[blockIdx.x * 256 + 128 + threadIdx.x] = rss[threadIdx.x] + rss[threadIdx.x + 128];
    }
}

// Parallel reduce of STATB partial blocks -> folded BN affine (scale, shift).
__global__ __launch_bounds__(1024) void k_bnfold(const float* __restrict__ partials,
                                                 const float* __restrict__ gamma,
                                                 const float* __restrict__ beta,
                                                 float invn, int nblk,
                                                 float* __restrict__ scale,
                                                 float* __restrict__ shift) {
    __shared__ float ls[8][128], lq[8][128];
    const int col = threadIdx.x & 127;
    const int grp = threadIdx.x >> 7;  // 0..7
    float s = 0.f, ss = 0.f;
#pragma unroll 4
    for (int b = grp; b < nblk; b += 8) {
        s += partials[b * 256 + col];
        ss += partials[b * 256 + 128 + col];
    }
    ls[grp][col] = s;
    lq[grp][col] = ss;
    __syncthreads();
    if (threadIdx.x < 128) {
        int c = threadIdx.x;
        float st = 0.f, sq = 0.f;
#pragma unroll
        for (int g = 0; g < 8; ++g) { st += ls[g][c]; sq += lq[g][c]; }
        float m = st * invn;
        float var = fmaf(-m, m, sq * invn);
        float sc = rsqrtf(var + BN_EPS) * gamma[c];
        scale[c] = sc;
        shift[c] = fmaf(-m, sc, beta[c]);
    }
}

// out = relu(x*scale + shift)
__global__ __launch_bounds__(256) void k_bnapply(const float* __restrict__ Bin,
                                                 float* __restrict__ out,
                                                 const float* __restrict__ scale,
                                                 const float* __restrict__ shift,
                                                 int n) {
    int idx = blockIdx.x * 256 + threadIdx.x;
    if (idx >= n * 32) return;
    int c4 = idx & 31;
    float4 x = ((const float4*)Bin)[idx];
    float4 sc = ((const float4*)scale)[c4];
    float4 sh = ((const float4*)shift)[c4];
    float4 o;
    o.x = fmaxf(fmaf(x.x, sc.x, sh.x), 0.f);
    o.y = fmaxf(fmaf(x.y, sc.y, sh.y), 0.f);
    o.z = fmaxf(fmaf(x.z, sc.z, sh.z), 0.f);
    o.w = fmaxf(fmaf(x.w, sc.w, sh.w), 0.f);
    ((float4*)out)[idx] = o;
}

// ---- fallback (atomic) path kernels ----
__global__ __launch_bounds__(256) void k_init_deg(int* __restrict__ deg, int n) {
    int i = blockIdx.x * 256 + threadIdx.x;
    if (i < n) deg[i] = 1;
}

__global__ __launch_bounds__(256) void k_count_deg(const void* __restrict__ eidx, int E,
                                                   const int* __restrict__ flag,
                                                   int* __restrict__ deg) {
    int e = blockIdx.x * 256 + threadIdx.x;
    if (e >= E) return;
    int d;
    if (*flag) d = (int)((const long long*)eidx)[E + e];
    else       d = ((const int*)eidx)[E + e];
    atomicAdd(&deg[d], 1);
}

__global__ __launch_bounds__(256) void k_dinv(const int* __restrict__ deg,
                                              float* __restrict__ dinv, int n) {
    int i = blockIdx.x * 256 + threadIdx.x;
    if (i < n) dinv[i] = rsqrtf((float)deg[i]);
}

__global__ __launch_bounds__(256) void k_selfloop(const float* __restrict__ H,
                                                  const float* __restrict__ dinv,
                                                  const float* __restrict__ bias,
                                                  float* __restrict__ B, int n) {
    int idx = blockIdx.x * 256 + threadIdx.x;
    if (idx >= n * 32) return;
    int r = idx >> 5, c = idx & 31;
    float s = dinv[r];
    s *= s;
    float4 h = ((const float4*)H)[idx];
    float4 bb = ((const float4*)bias)[c];
    float4 o{fmaf(h.x, s, bb.x), fmaf(h.y, s, bb.y),
             fmaf(h.z, s, bb.z), fmaf(h.w, s, bb.w)};
    ((float4*)B)[idx] = o;
}

__global__ __launch_bounds__(256) void k_edge(const void* __restrict__ eidx, int E,
                                              const int* __restrict__ flag,
                                              const float* __restrict__ dinv,
                                              const float* __restrict__ H,
                                              float* __restrict__ B) {
    int e = blockIdx.x * 8 + (threadIdx.x >> 5);
    if (e >= E) return;
    int lane = threadIdx.x & 31;
    int s, d;
    if (*flag) {
        s = (int)((const long long*)eidx)[e];
        d = (int)((const long long*)eidx)[E + e];
    } else {
        s = ((const int*)eidx)[e];
        d = ((const int*)eidx)[E + e];
    }
    float nrm = dinv[s] * dinv[d];
    float4 h = ((const float4*)(H + (size_t)s * 128))[lane];
    float* out = B + (size_t)d * 128 + lane * 4;
    atomicAdd(out + 0, h.x * nrm);
    atomicAdd(out + 1, h.y * nrm);
    atomicAdd(out + 2, h.z * nrm);
    atomicAdd(out + 3, h.w * nrm);
}

static inline char* align256(char* p) {
    return (char*)(((uintptr_t)p + 255) & ~(uintptr_t)255);
}

extern "C" void kernel_launch(void* const* d_in, const int* in_sizes, int n_in,
                              void* d_out, int out_size, void* d_ws, size_t ws_size,
                              hipStream_t stream) {
    const float* x   = (const float*)d_in[0];
    const void*  ei  = d_in[1];
    const float* W1  = (const float*)d_in[2];
    const float* b1  = (const float*)d_in[3];
    const float* g1  = (const float*)d_in[4];
    const float* be1 = (const float*)d_in[5];
    const float* W2  = (const float*)d_in[6];
    const float* b2  = (const float*)d_in[7];
    const float* g2  = (const float*)d_in[8];
    const float* be2 = (const float*)d_in[9];

    const int n = in_sizes[0] / 128;
    const int E = in_sizes[1] / 2;
    const float invn = 1.0f / (float)n;
    float* out = (float*)d_out;

    const int nb_n   = (n + 255) / 256;
    const int nb_e   = (E + 255) / 256;
    const int nb_e4  = (E + 1023) / 1024;   // k_ell: 4 edges/thread
    const int nb_el  = (n * 32 + 255) / 256;
    const int nb_gm  = (n + 63) / 64;
    const int nb_gf  = (n + 31) / 32;
    const int nb_edge = (E + 7) / 8;
    const int nb_agg = (n + 3) / 4;

    // ---- main (ELL) layout ----
    char* p = (char*)d_ws;
    float* B = (float*)p;                      p += (size_t)n * 128 * 4;
    unsigned short* Ab = (unsigned short*)p;   p += (size_t)n * 128 * 2;
    p = align256(p);
    int* rec = (int*)p;                        p += (size_t)n * ELLW * 4;
    int2* ovf = (int2*)p;                      p += (size_t)E * 8;
    int* deg = (int*)p;                        p += (size_t)n * 4;
    int* ovf_cnt = (int*)p;                    p += 4;
    p = align256(p);
    float* partials = (float*)p;               p += (size_t)STATB * 256 * 4;
    float* scale = (float*)p;                  p += 128 * 4;
    float* shift = (float*)p;                  p += 128 * 4;
    int* flag = (int*)p;                       p += 16;
    const bool ell_ok = (size_t)(p - (char*)d_ws) <= ws_size;

    if (ell_ok) {
        k_detect_i64<<<1, 256, 0, stream>>>((const unsigned*)ei, flag);
        hipMemsetAsync(deg, 0, (size_t)n * 4 + 4, stream);  // deg + ovf_cnt
        k_ell<<<nb_e4, 256, 0, stream>>>(ei, E, flag, deg, rec, ovf, ovf_cnt, E);

        // ---- layer 1 ----
        k_gemm_mfma<<<nb_gm, 256, 0, stream>>>(x, W1, n, nullptr, nullptr, Ab, nullptr);
        k_agg<<<nb_agg, 256, 0, stream>>>(rec, deg, (const unsigned*)Ab, b1, B, n);
        k_ovf<<<16, 256, 0, stream>>>(ovf, ovf_cnt, deg, (const unsigned*)Ab, B, E);
        k_bnstats<<<STATB, 256, 0, stream>>>(B, n, partials);
        k_bnfold<<<1, 1024, 0, stream>>>(partials, g1, be1, invn, STATB, scale, shift);

        // ---- layer 2 (BN1+ReLU folded into GEMM staging) ----
        k_gemm_mfma<<<nb_gm, 256, 0, stream>>>(B, W2, n, scale, shift, Ab, nullptr);
        k_agg<<<nb_agg, 256, 0, stream>>>(rec, deg, (const unsigned*)Ab, b2, B, n);
        k_ovf<<<16, 256, 0, stream>>>(ovf, ovf_cnt, deg, (const unsigned*)Ab, B, E);
        k_bnstats<<<STATB, 256, 0, stream>>>(B, n, partials);
        k_bnfold<<<1, 1024, 0, stream>>>(partials, g2, be2, invn, STATB, scale, shift);
        k_bnapply<<<nb_el, 256, 0, stream>>>(B, out, scale, shift, n);
    } else {
        // ---- fallback: atomic scatter path (f32 H) ----
        char* q = (char*)d_ws;
        float* A = (float*)q;        q += (size_t)n * 128 * 4;
        float* Bf = (float*)q;       q += (size_t)n * 128 * 4;
        int* degf = (int*)q;         q += (size_t)n * 4;
        float* dinv = (float*)q;     q += (size_t)n * 4;
        q = align256(q);
        float* part = (float*)q;     q += (size_t)STATB * 256 * 4;
        float* sc = (float*)q;       q += 128 * 4;
        float* sh = (float*)q;       q += 128 * 4;
        int* flg = (int*)q;          q += 16;

        k_detect_i64<<<1, 256, 0, stream>>>((const unsigned*)ei, flg);
        k_init_deg<<<nb_n, 256, 0, stream>>>(degf, n);
        k_count_deg<<<nb_e, 256, 0, stream>>>(ei, E, flg, degf);
        k_dinv<<<nb_n, 256, 0, stream>>>(degf, dinv, n);

        k_gemm_f32<<<nb_gf, 256, 0, stream>>>(x, W1, n, A);
        k_selfloop<<<nb_el, 256, 0, stream>>>(A, dinv, b1, Bf, n);
        k_edge<<<nb_edge, 256, 0, stream>>>(ei, E, flg, dinv, A, Bf);
        k_bnstats<<<STATB, 256, 0, stream>>>(Bf, n, part);
        k_bnfold<<<1, 1024, 0, stream>>>(part, g1, be1, invn, STATB, sc, sh);
        k_bnapply<<<nb_el, 256, 0, stream>>>(Bf, Bf, sc, sh, n);

        k_gemm_f32<<<nb_gf, 256, 0, stream>>>(Bf, W2, n, A);
        k_selfloop<<<nb_el, 256, 0, stream>>>(A, dinv, b2, Bf, n);
        k_edge<<<nb_edge, 256, 0, stream>>>(ei, E, flg, dinv, A, Bf);
        k_bnstats<<<STATB, 256, 0, stream>>>(Bf, n, part);
        k_bnfold<<<1, 1024, 0, stream>>>(part, g2, be2, invn, STATB, sc, sh);
        k_bnapply<<<nb_el, 256, 0, stream>>>(Bf, out, sc, sh, n);
    }
}

// Round 15
// 226.611 us; speedup vs baseline: 1.2502x; 1.0172x over previous
//
#include <hip/hip_runtime.h>

static constexpr float BN_EPS = 1e-5f;
#define ELLW 64
#define STATB 512   // k_bnstats grid

typedef short short8 __attribute__((ext_vector_type(8)));
typedef float f32x4 __attribute__((ext_vector_type(4)));
union BF8 { short8 v; unsigned u[4]; uint4 q; };

__device__ __forceinline__ unsigned rne_bf16(float f) {
    unsigned u = __float_as_uint(f);
    u += 0x7fffu + ((u >> 16) & 1u);
    return u >> 16;
}
__device__ __forceinline__ float bflo(unsigned u) { return __uint_as_float(u << 16); }
__device__ __forceinline__ float bfhi(unsigned u) { return __uint_as_float(u & 0xffff0000u); }

// Detect whether edge_index is int64 (high words all zero) or int32.
__global__ __launch_bounds__(256) void k_detect_i64(const unsigned* __restrict__ ei,
                                                    int* __restrict__ flag) {
    if (blockIdx.x == 0 && threadIdx.x == 0) {
        int allz = 1;
        for (int i = 0; i < 256; ++i) {
            if (ei[2 * i + 1] != 0u) { allz = 0; break; }
        }
        *flag = allz;
    }
}

// ELL build body: 4 edges per thread (strided), 4 independent atomic->store
// chains in flight. Direct random scatter (R12: beats CSR & 2-phase bucketing).
__device__ __forceinline__ void ell_body(const void* __restrict__ eidx, int E,
                                         const int* __restrict__ flag,
                                         int* __restrict__ deg,
                                         int* __restrict__ rec,
                                         int2* __restrict__ ovf,
                                         int* __restrict__ ovf_cnt, int ovf_cap,
                                         int blk) {
    const int base = blk * 1024 + threadIdx.x;
    const bool is64 = (*flag != 0);
    int s[4], d[4];
    bool ok[4];
#pragma unroll
    for (int j = 0; j < 4; ++j) {
        int e = base + j * 256;
        ok[j] = e < E;
        if (ok[j]) {
            if (is64) {
                s[j] = (int)((const long long*)eidx)[e];
                d[j] = (int)((const long long*)eidx)[E + e];
            } else {
                s[j] = ((const int*)eidx)[e];
                d[j] = ((const int*)eidx)[E + e];
            }
        }
    }
    int pos[4];
#pragma unroll
    for (int j = 0; j < 4; ++j)
        if (ok[j]) pos[j] = atomicAdd(&deg[d[j]], 1);
#pragma unroll
    for (int j = 0; j < 4; ++j) {
        if (!ok[j]) continue;
        if (pos[j] < ELLW) {
            rec[(size_t)d[j] * ELLW + pos[j]] = s[j];
        } else {
            int o = atomicAdd(ovf_cnt, 1);
            if (o < ovf_cap) ovf[o] = make_int2(s[j], d[j]);
        }
    }
}

// MFMA bf16x3 split-precision GEMM body: Y[row0:row0+64,:] = act(X) @ W.
// act = relu(x*scale+shift) if scale != nullptr. Output bf16 (Yb) / f32 (Yf).
__device__ __forceinline__ void gemm_body(const float* __restrict__ X,
                                          const float* __restrict__ W,
                                          int n,
                                          const float* __restrict__ scale,
                                          const float* __restrict__ shift,
                                          unsigned short* __restrict__ Yb,
                                          float* __restrict__ Yf,
                                          int row0) {
    __shared__ unsigned short Xh[64][136];
    __shared__ unsigned short Xl[64][136];
    const int tid = threadIdx.x;
    const int lane = tid & 63;
    const int w = tid >> 6;
    const int kb = (lane >> 4) * 8;
    const int cl16 = lane & 15;

    BF8 Bh[4][2], Bl[4][2];
#pragma unroll
    for (int ks = 0; ks < 4; ++ks) {
#pragma unroll
        for (int nn = 0; nn < 2; ++nn) {
            const float* wp = W + (size_t)(ks * 32 + kb) * 128 + w * 32 + nn * 16 + cl16;
            unsigned uh[8], ul[8];
#pragma unroll
            for (int j = 0; j < 8; ++j) {
                float v = wp[(size_t)j * 128];
                unsigned h = rne_bf16(v);
                unsigned l = rne_bf16(v - __uint_as_float(h << 16));
                uh[j] = h; ul[j] = l;
            }
#pragma unroll
            for (int t = 0; t < 4; ++t) {
                Bh[ks][nn].u[t] = uh[2 * t] | (uh[2 * t + 1] << 16);
                Bl[ks][nn].u[t] = ul[2 * t] | (ul[2 * t + 1] << 16);
            }
        }
    }

    for (int i = tid; i < 64 * 32; i += 256) {
        int r = i >> 5, c = i & 31;
        int gr = row0 + r;
        float4 v = (gr < n) ? ((const float4*)X)[(size_t)gr * 32 + c]
                            : float4{0.f, 0.f, 0.f, 0.f};
        if (scale) {
            float4 sc = ((const float4*)scale)[c];
            float4 sh = ((const float4*)shift)[c];
            v.x = fmaxf(fmaf(v.x, sc.x, sh.x), 0.f);
            v.y = fmaxf(fmaf(v.y, sc.y, sh.y), 0.f);
            v.z = fmaxf(fmaf(v.z, sc.z, sh.z), 0.f);
            v.w = fmaxf(fmaf(v.w, sc.w, sh.w), 0.f);
        }
#pragma unroll
        for (int j = 0; j < 4; ++j) {
            float f = (&v.x)[j];
            unsigned h = rne_bf16(f);
            unsigned l = rne_bf16(f - __uint_as_float(h << 16));
            Xh[r][c * 4 + j] = (unsigned short)h;
            Xl[r][c * 4 + j] = (unsigned short)l;
        }
    }
    __syncthreads();

    f32x4 acc[4][2];
#pragma unroll
    for (int m = 0; m < 4; ++m)
#pragma unroll
        for (int nn = 0; nn < 2; ++nn) acc[m][nn] = f32x4{0.f, 0.f, 0.f, 0.f};
#pragma unroll
    for (int ks = 0; ks < 4; ++ks) {
        BF8 Ah[4], Al[4];
#pragma unroll
        for (int m = 0; m < 4; ++m) {
            const int r = m * 16 + cl16;
            const int cc = ks * 32 + kb;
            Ah[m].q = *(const uint4*)&Xh[r][cc];
            Al[m].q = *(const uint4*)&Xl[r][cc];
        }
#pragma unroll
        for (int m = 0; m < 4; ++m) {
#pragma unroll
            for (int nn = 0; nn < 2; ++nn) {
                acc[m][nn] = __builtin_amdgcn_mfma_f32_16x16x32_bf16(Ah[m].v, Bh[ks][nn].v, acc[m][nn], 0, 0, 0);
                acc[m][nn] = __builtin_amdgcn_mfma_f32_16x16x32_bf16(Ah[m].v, Bl[ks][nn].v, acc[m][nn], 0, 0, 0);
                acc[m][nn] = __builtin_amdgcn_mfma_f32_16x16x32_bf16(Al[m].v, Bh[ks][nn].v, acc[m][nn], 0, 0, 0);
            }
        }
    }

    const int rb2 = (lane >> 4) * 4;
#pragma unroll
    for (int m = 0; m < 4; ++m) {
#pragma unroll
        for (int nn = 0; nn < 2; ++nn) {
            const int col = w * 32 + nn * 16 + cl16;
#pragma unroll
            for (int r = 0; r < 4; ++r) {
                int gr = row0 + m * 16 + rb2 + r;
                if (gr < n) {
                    float val = acc[m][nn][r];
                    if (Yb) Yb[(size_t)gr * 128 + col] = (unsigned short)rne_bf16(val);
                    if (Yf) Yf[(size_t)gr * 128 + col] = val;
                }
            }
        }
    }
}

// Standalone GEMM (layer 2).
__global__ __launch_bounds__(256) void k_gemm_mfma(const float* __restrict__ X,
                                                   const float* __restrict__ W,
                                                   int n,
                                                   const float* __restrict__ scale,
                                                   const float* __restrict__ shift,
                                                   unsigned short* __restrict__ Yb,
                                                   float* __restrict__ Yf) {
    gemm_body(X, W, n, scale, shift, Yb, Yf, blockIdx.x * 64);
}

// Fat kernel: GEMM1 blocks [0,nb_gm) run concurrently with ELL-build blocks
// [nb_gm, nb_gm+nb_ell). The two roles are independent (GEMM reads x,W1;
// ELL reads edge_index) and contend for almost disjoint resources
// (MFMA/LDS/streaming-BW vs latency-bound scatter).
__global__ __launch_bounds__(256) void k_ell_gemm(const float* __restrict__ X,
                                                  const float* __restrict__ W,
                                                  int n,
                                                  unsigned short* __restrict__ Yb,
                                                  int nb_gm,
                                                  const void* __restrict__ eidx, int E,
                                                  const int* __restrict__ flag,
                                                  int* __restrict__ deg,
                                                  int* __restrict__ rec,
                                                  int2* __restrict__ ovf,
                                                  int* __restrict__ ovf_cnt, int ovf_cap) {
    const int bid = (int)blockIdx.x;
    if (bid < nb_gm) {
        gemm_body(X, W, n, nullptr, nullptr, Yb, nullptr, bid * 64);
    } else {
        ell_body(eidx, E, flag, deg, rec, ovf, ovf_cnt, ovf_cap, bid - nb_gm);
    }
}

// f32 GEMM (fallback path only).
__global__ __launch_bounds__(256) void k_gemm_f32(const float* __restrict__ X,
                                                  const float* __restrict__ W,
                                                  int n,
                                                  float* __restrict__ Yf) {
    __shared__ float Ws[128 * 128];
    __shared__ float Xs[32 * 128];
    const int tid = threadIdx.x;
    for (int i = tid; i < 128 * 32; i += 256)
        ((float4*)Ws)[i] = ((const float4*)W)[i];
    const int row0 = blockIdx.x * 32;
    for (int i = tid; i < 32 * 32; i += 256) {
        int r = i >> 5, c = i & 31;
        int gr = row0 + r;
        float4 v = (gr < n) ? ((const float4*)X)[(size_t)gr * 32 + c]
                            : float4{0.f, 0.f, 0.f, 0.f};
        ((float4*)Xs)[i] = v;
    }
    __syncthreads();
    const int c4 = (tid & 31) * 4;
    const int rb = tid >> 5;
    float4 acc[4];
#pragma unroll
    for (int j = 0; j < 4; ++j) acc[j] = float4{0.f, 0.f, 0.f, 0.f};
    for (int k = 0; k < 128; ++k) {
        float4 w = *(const float4*)&Ws[k * 128 + c4];
#pragma unroll
        for (int j = 0; j < 4; ++j) {
            float xv = Xs[(rb + 8 * j) * 128 + k];
            acc[j].x = fmaf(xv, w.x, acc[j].x);
            acc[j].y = fmaf(xv, w.y, acc[j].y);
            acc[j].z = fmaf(xv, w.z, acc[j].z);
            acc[j].w = fmaf(xv, w.w, acc[j].w);
        }
    }
#pragma unroll
    for (int j = 0; j < 4; ++j) {
        int r = row0 + rb + 8 * j;
        if (r < n) *(float4*)&Yf[(size_t)r * 128 + c4] = acc[j];
    }
}

// One wave per dst row (R10 structure, verbatim).
__global__ __launch_bounds__(256) void k_agg(const int* __restrict__ rec,
                                             const int* __restrict__ deg,
                                             const unsigned* __restrict__ Hb,
                                             const float* __restrict__ bias,
                                             float* __restrict__ B, int n) {
    const int d = blockIdx.x * 4 + (threadIdx.x >> 6);
    if (d >= n) return;
    const int lane = threadIdx.x & 63;
    const int cnt = __builtin_amdgcn_readfirstlane(deg[d]);
    const int cl = cnt < ELLW ? cnt : ELLW;
    const float dinv_d = rsqrtf((float)(cnt + 1));
    const float selfn = dinv_d * dinv_d;
    unsigned hu = Hb[(size_t)d * 64 + lane];
    float2 bb = ((const float2*)bias)[lane];
    float accx = fmaf(bflo(hu), selfn, bb.x);
    float accy = fmaf(bfhi(hu), selfn, bb.y);
    const int* row = rec + (size_t)d * ELLW;
    int e = 0;
    for (; e + 3 < cl; e += 4) {
        int4 ra = *(const int4*)&row[e];
        float n0 = rsqrtf((float)(deg[ra.x] + 1)) * dinv_d;
        float n1 = rsqrtf((float)(deg[ra.y] + 1)) * dinv_d;
        float n2 = rsqrtf((float)(deg[ra.z] + 1)) * dinv_d;
        float n3 = rsqrtf((float)(deg[ra.w] + 1)) * dinv_d;
        unsigned u0 = Hb[(size_t)ra.x * 64 + lane];
        unsigned u1 = Hb[(size_t)ra.y * 64 + lane];
        unsigned u2 = Hb[(size_t)ra.z * 64 + lane];
        unsigned u3 = Hb[(size_t)ra.w * 64 + lane];
        accx = fmaf(bflo(u0), n0, accx); accy = fmaf(bfhi(u0), n0, accy);
        accx = fmaf(bflo(u1), n1, accx); accy = fmaf(bfhi(u1), n1, accy);
        accx = fmaf(bflo(u2), n2, accx); accy = fmaf(bfhi(u2), n2, accy);
        accx = fmaf(bflo(u3), n3, accx); accy = fmaf(bfhi(u3), n3, accy);
    }
    for (; e < cl; ++e) {
        int r = row[e];
        float n0 = rsqrtf((float)(deg[r] + 1)) * dinv_d;
        unsigned u0 = Hb[(size_t)r * 64 + lane];
        accx = fmaf(bflo(u0), n0, accx); accy = fmaf(bfhi(u0), n0, accy);
    }
    ((float2*)(B + (size_t)d * 128))[lane] = make_float2(accx, accy);
}

// Replay overflow edges (normally zero) with f32 atomics.
__global__ __launch_bounds__(256) void k_ovf(const int2* __restrict__ ovf,
                                             const int* __restrict__ ovf_cnt,
                                             const int* __restrict__ deg,
                                             const unsigned* __restrict__ Hb,
                                             float* __restrict__ B, int ovf_cap) {
    int m = *ovf_cnt;
    if (m > ovf_cap) m = ovf_cap;
    const int lane = threadIdx.x & 63;
    for (int i = blockIdx.x * 4 + (threadIdx.x >> 6); i < m; i += gridDim.x * 4) {
        int2 sd = ovf[i];
        float nrm = rsqrtf((float)(deg[sd.x] + 1)) * rsqrtf((float)(deg[sd.y] + 1));
        unsigned u = Hb[(size_t)sd.x * 64 + lane];
        atomicAdd(&B[(size_t)sd.y * 128 + 2 * lane], bflo(u) * nrm);
        atomicAdd(&B[(size_t)sd.y * 128 + 2 * lane + 1], bfhi(u) * nrm);
    }
}

// Per-block column partials (non-atomic); grid = STATB blocks.
__global__ __launch_bounds__(256) void k_bnstats(const float* __restrict__ B, int n,
                                                 float* __restrict__ partials) {
    __shared__ float rs[256], rss[256];
    int col = threadIdx.x & 127;
    int rg = threadIdx.x >> 7;
    float s = 0.f, ss = 0.f;
    for (int r = blockIdx.x * 2 + rg; r < n; r += gridDim.x * 2) {
        float v = B[(size_t)r * 128 + col];
        s += v;
        ss = fmaf(v, v, ss);
    }
    rs[threadIdx.x] = s;
    rss[threadIdx.x] = ss;
    __syncthreads();
    if (threadIdx.x < 128) {
        partials[blockIdx.x * 256 + threadIdx.x] = rs[threadIdx.x] + rs[threadIdx.x + 128];
        partials[blockIdx.x * 256 + 128 + threadIdx.x] = rss[threadIdx.x] + rss[threadIdx.x + 128];
    }
}

// Parallel reduce of STATB partial blocks -> folded BN affine (scale, shift).
__global__ __launch_bounds__(1024) void k_bnfold(const float* __restrict__ partials,
                                                 const float* __restrict__ gamma,
                                                 const float* __restrict__ beta,
                                                 float invn, int nblk,
                                                 float* __restrict__ scale,
                                                 float* __restrict__ shift) {
    __shared__ float ls[8][128], lq[8][128];
    const int col = threadIdx.x & 127;
    const int grp = threadIdx.x >> 7;  // 0..7
    float s = 0.f, ss = 0.f;
#pragma unroll 4
    for (int b = grp; b < nblk; b += 8) {
        s += partials[b * 256 + col];
        ss += partials[b * 256 + 128 + col];
    }
    ls[grp][col] = s;
    lq[grp][col] = ss;
    __syncthreads();
    if (threadIdx.x < 128) {
        int c = threadIdx.x;
        float st = 0.f, sq = 0.f;
#pragma unroll
        for (int g = 0; g < 8; ++g) { st += ls[g][c]; sq += lq[g][c]; }
        float m = st * invn;
        float var = fmaf(-m, m, sq * invn);
        float sc = rsqrtf(var + BN_EPS) * gamma[c];
        scale[c] = sc;
        shift[c] = fmaf(-m, sc, beta[c]);
    }
}

// out = relu(x*scale + shift)
__global__ __launch_bounds__(256) void k_bnapply(const float* __restrict__ Bin,
                                                 float* __restrict__ out,
                                                 const float* __restrict__ scale,
                                                 const float* __restrict__ shift,
                                                 int n) {
    int idx = blockIdx.x * 256 + threadIdx.x;
    if (idx >= n * 32) return;
    int c4 = idx & 31;
    float4 x = ((const float4*)Bin)[idx];
    float4 sc = ((const float4*)scale)[c4];
    float4 sh = ((const float4*)shift)[c4];
    float4 o;
    o.x = fmaxf(fmaf(x.x, sc.x, sh.x), 0.f);
    o.y = fmaxf(fmaf(x.y, sc.y, sh.y), 0.f);
    o.z = fmaxf(fmaf(x.z, sc.z, sh.z), 0.f);
    o.w = fmaxf(fmaf(x.w, sc.w, sh.w), 0.f);
    ((float4*)out)[idx] = o;
}

// ---- fallback (atomic) path kernels ----
__global__ __launch_bounds__(256) void k_init_deg(int* __restrict__ deg, int n) {
    int i = blockIdx.x * 256 + threadIdx.x;
    if (i < n) deg[i] = 1;
}

__global__ __launch_bounds__(256) void k_count_deg(const void* __restrict__ eidx, int E,
                                                   const int* __restrict__ flag,
                                                   int* __restrict__ deg) {
    int e = blockIdx.x * 256 + threadIdx.x;
    if (e >= E) return;
    int d;
    if (*flag) d = (int)((const long long*)eidx)[E + e];
    else       d = ((const int*)eidx)[E + e];
    atomicAdd(&deg[d], 1);
}

__global__ __launch_bounds__(256) void k_dinv(const int* __restrict__ deg,
                                              float* __restrict__ dinv, int n) {
    int i = blockIdx.x * 256 + threadIdx.x;
    if (i < n) dinv[i] = rsqrtf((float)deg[i]);
}

__global__ __launch_bounds__(256) void k_selfloop(const float* __restrict__ H,
                                                  const float* __restrict__ dinv,
                                                  const float* __restrict__ bias,
                                                  float* __restrict__ B, int n) {
    int idx = blockIdx.x * 256 + threadIdx.x;
    if (idx >= n * 32) return;
    int r = idx >> 5, c = idx & 31;
    float s = dinv[r];
    s *= s;
    float4 h = ((const float4*)H)[idx];
    float4 bb = ((const float4*)bias)[c];
    float4 o{fmaf(h.x, s, bb.x), fmaf(h.y, s, bb.y),
             fmaf(h.z, s, bb.z), fmaf(h.w, s, bb.w)};
    ((float4*)B)[idx] = o;
}

__global__ __launch_bounds__(256) void k_edge(const void* __restrict__ eidx, int E,
                                              const int* __restrict__ flag,
                                              const float* __restrict__ dinv,
                                              const float* __restrict__ H,
                                              float* __restrict__ B) {
    int e = blockIdx.x * 8 + (threadIdx.x >> 5);
    if (e >= E) return;
    int lane = threadIdx.x & 31;
    int s, d;
    if (*flag) {
        s = (int)((const long long*)eidx)[e];
        d = (int)((const long long*)eidx)[E + e];
    } else {
        s = ((const int*)eidx)[e];
        d = ((const int*)eidx)[E + e];
    }
    float nrm = dinv[s] * dinv[d];
    float4 h = ((const float4*)(H + (size_t)s * 128))[lane];
    float* out = B + (size_t)d * 128 + lane * 4;
    atomicAdd(out + 0, h.x * nrm);
    atomicAdd(out + 1, h.y * nrm);
    atomicAdd(out + 2, h.z * nrm);
    atomicAdd(out + 3, h.w * nrm);
}

static inline char* align256(char* p) {
    return (char*)(((uintptr_t)p + 255) & ~(uintptr_t)255);
}

extern "C" void kernel_launch(void* const* d_in, const int* in_sizes, int n_in,
                              void* d_out, int out_size, void* d_ws, size_t ws_size,
                              hipStream_t stream) {
    const float* x   = (const float*)d_in[0];
    const void*  ei  = d_in[1];
    const float* W1  = (const float*)d_in[2];
    const float* b1  = (const float*)d_in[3];
    const float* g1  = (const float*)d_in[4];
    const float* be1 = (const float*)d_in[5];
    const float* W2  = (const float*)d_in[6];
    const float* b2  = (const float*)d_in[7];
    const float* g2  = (const float*)d_in[8];
    const float* be2 = (const float*)d_in[9];

    const int n = in_sizes[0] / 128;
    const int E = in_sizes[1] / 2;
    const float invn = 1.0f / (float)n;
    float* out = (float*)d_out;

    const int nb_n   = (n + 255) / 256;
    const int nb_e   = (E + 255) / 256;
    const int nb_e4  = (E + 1023) / 1024;   // ell: 4 edges/thread
    const int nb_el  = (n * 32 + 255) / 256;
    const int nb_gm  = (n + 63) / 64;
    const int nb_gf  = (n + 31) / 32;
    const int nb_edge = (E + 7) / 8;
    const int nb_agg = (n + 3) / 4;

    // ---- main (ELL) layout ----
    char* p = (char*)d_ws;
    float* B = (float*)p;                      p += (size_t)n * 128 * 4;
    unsigned short* Ab = (unsigned short*)p;   p += (size_t)n * 128 * 2;
    p = align256(p);
    int* rec = (int*)p;                        p += (size_t)n * ELLW * 4;
    int2* ovf = (int2*)p;                      p += (size_t)E * 8;
    int* deg = (int*)p;                        p += (size_t)n * 4;
    int* ovf_cnt = (int*)p;                    p += 4;
    p = align256(p);
    float* partials = (float*)p;               p += (size_t)STATB * 256 * 4;
    float* scale = (float*)p;                  p += 128 * 4;
    float* shift = (float*)p;                  p += 128 * 4;
    int* flag = (int*)p;                       p += 16;
    const bool ell_ok = (size_t)(p - (char*)d_ws) <= ws_size;

    if (ell_ok) {
        k_detect_i64<<<1, 256, 0, stream>>>((const unsigned*)ei, flag);
        hipMemsetAsync(deg, 0, (size_t)n * 4 + 4, stream);  // deg + ovf_cnt

        // ---- layer 1: GEMM1 and ELL-build fused (independent roles) ----
        k_ell_gemm<<<nb_gm + nb_e4, 256, 0, stream>>>(x, W1, n, Ab, nb_gm,
                                                      ei, E, flag, deg, rec,
                                                      ovf, ovf_cnt, E);
        k_agg<<<nb_agg, 256, 0, stream>>>(rec, deg, (const unsigned*)Ab, b1, B, n);
        k_ovf<<<16, 256, 0, stream>>>(ovf, ovf_cnt, deg, (const unsigned*)Ab, B, E);
        k_bnstats<<<STATB, 256, 0, stream>>>(B, n, partials);
        k_bnfold<<<1, 1024, 0, stream>>>(partials, g1, be1, invn, STATB, scale, shift);

        // ---- layer 2 (BN1+ReLU folded into GEMM staging) ----
        k_gemm_mfma<<<nb_gm, 256, 0, stream>>>(B, W2, n, scale, shift, Ab, nullptr);
        k_agg<<<nb_agg, 256, 0, stream>>>(rec, deg, (const unsigned*)Ab, b2, B, n);
        k_ovf<<<16, 256, 0, stream>>>(ovf, ovf_cnt, deg, (const unsigned*)Ab, B, E);
        k_bnstats<<<STATB, 256, 0, stream>>>(B, n, partials);
        k_bnfold<<<1, 1024, 0, stream>>>(partials, g2, be2, invn, STATB, scale, shift);
        k_bnapply<<<nb_el, 256, 0, stream>>>(B, out, scale, shift, n);
    } else {
        // ---- fallback: atomic scatter path (f32 H) ----
        char* q = (char*)d_ws;
        float* A = (float*)q;        q += (size_t)n * 128 * 4;
        float* Bf = (float*)q;       q += (size_t)n * 128 * 4;
        int* degf = (int*)q;         q += (size_t)n * 4;
        float* dinv = (float*)q;     q += (size_t)n * 4;
        q = align256(q);
        float* part = (float*)q;     q += (size_t)STATB * 256 * 4;
        float* sc = (float*)q;       q += 128 * 4;
        float* sh = (float*)q;       q += 128 * 4;
        int* flg = (int*)q;          q += 16;

        k_detect_i64<<<1, 256, 0, stream>>>((const unsigned*)ei, flg);
        k_init_deg<<<nb_n, 256, 0, stream>>>(degf, n);
        k_count_deg<<<nb_e, 256, 0, stream>>>(ei, E, flg, degf);
        k_dinv<<<nb_n, 256, 0, stream>>>(degf, dinv, n);

        k_gemm_f32<<<nb_gf, 256, 0, stream>>>(x, W1, n, A);
        k_selfloop<<<nb_el, 256, 0, stream>>>(A, dinv, b1, Bf, n);
        k_edge<<<nb_edge, 256, 0, stream>>>(ei, E, flg, dinv, A, Bf);
        k_bnstats<<<STATB, 256, 0, stream>>>(Bf, n, part);
        k_bnfold<<<1, 1024, 0, stream>>>(part, g1, be1, invn, STATB, sc, sh);
        k_bnapply<<<nb_el, 256, 0, stream>>>(Bf, Bf, sc, sh, n);

        k_gemm_f32<<<nb_gf, 256, 0, stream>>>(Bf, W2, n, A);
        k_selfloop<<<nb_el, 256, 0, stream>>>(A, dinv, b2, Bf, n);
        k_edge<<<nb_edge, 256, 0, stream>>>(ei, E, flg, dinv, A, Bf);
        k_bnstats<<<STATB, 256, 0, stream>>>(Bf, n, part);
        k_bnfold<<<1, 1024, 0, stream>>>(part, g2, be2, invn, STATB, sc, sh);
        k_bnapply<<<nb_el, 256, 0, stream>>>(Bf, out, sc, sh, n);
    }
}

// Round 16
// 223.203 us; speedup vs baseline: 1.2693x; 1.0153x over previous
//
#include <hip/hip_runtime.h>

static constexpr float BN_EPS = 1e-5f;
#define ELLW 64
#define STATB 512   // k_bnstats grid

typedef short short8 __attribute__((ext_vector_type(8)));
typedef float f32x4 __attribute__((ext_vector_type(4)));
union BF8 { short8 v; unsigned u[4]; uint4 q; };

__device__ __forceinline__ unsigned rne_bf16(float f) {
    unsigned u = __float_as_uint(f);
    u += 0x7fffu + ((u >> 16) & 1u);
    return u >> 16;
}
__device__ __forceinline__ float bflo(unsigned u) { return __uint_as_float(u << 16); }
__device__ __forceinline__ float bfhi(unsigned u) { return __uint_as_float(u & 0xffff0000u); }

// Detect whether edge_index is int64 (high words all zero) or int32.
__global__ __launch_bounds__(256) void k_detect_i64(const unsigned* __restrict__ ei,
                                                    int* __restrict__ flag) {
    if (blockIdx.x == 0 && threadIdx.x == 0) {
        int allz = 1;
        for (int i = 0; i < 256; ++i) {
            if (ei[2 * i + 1] != 0u) { allz = 0; break; }
        }
        *flag = allz;
    }
}

// ELL build body: 8 edges per thread (strided) -> 8 independent atomic->store
// chains in flight (compensates the fat-kernel's reduced occupancy).
// Direct random scatter (R12: beats CSR & 2-phase bucketing).
__device__ __forceinline__ void ell_body(const void* __restrict__ eidx, int E,
                                         const int* __restrict__ flag,
                                         int* __restrict__ deg,
                                         int* __restrict__ rec,
                                         int2* __restrict__ ovf,
                                         int* __restrict__ ovf_cnt, int ovf_cap,
                                         int blk) {
    const int base = blk * 2048 + threadIdx.x;
    const bool is64 = (*flag != 0);
    int s[8], d[8];
    bool ok[8];
#pragma unroll
    for (int j = 0; j < 8; ++j) {
        int e = base + j * 256;
        ok[j] = e < E;
        if (ok[j]) {
            if (is64) {
                s[j] = (int)((const long long*)eidx)[e];
                d[j] = (int)((const long long*)eidx)[E + e];
            } else {
                s[j] = ((const int*)eidx)[e];
                d[j] = ((const int*)eidx)[E + e];
            }
        }
    }
    int pos[8];
#pragma unroll
    for (int j = 0; j < 8; ++j)
        if (ok[j]) pos[j] = atomicAdd(&deg[d[j]], 1);
#pragma unroll
    for (int j = 0; j < 8; ++j) {
        if (!ok[j]) continue;
        if (pos[j] < ELLW) {
            rec[(size_t)d[j] * ELLW + pos[j]] = s[j];
        } else {
            int o = atomicAdd(ovf_cnt, 1);
            if (o < ovf_cap) ovf[o] = make_int2(s[j], d[j]);
        }
    }
}

// MFMA bf16x3 split-precision GEMM body: Y[row0:row0+64,:] = act(X) @ W.
// act = relu(x*scale+shift) if scale != nullptr. Output bf16 (Yb) / f32 (Yf).
__device__ __forceinline__ void gemm_body(const float* __restrict__ X,
                                          const float* __restrict__ W,
                                          int n,
                                          const float* __restrict__ scale,
                                          const float* __restrict__ shift,
                                          unsigned short* __restrict__ Yb,
                                          float* __restrict__ Yf,
                                          int row0) {
    __shared__ unsigned short Xh[64][136];
    __shared__ unsigned short Xl[64][136];
    const int tid = threadIdx.x;
    const int lane = tid & 63;
    const int w = tid >> 6;
    const int kb = (lane >> 4) * 8;
    const int cl16 = lane & 15;

    BF8 Bh[4][2], Bl[4][2];
#pragma unroll
    for (int ks = 0; ks < 4; ++ks) {
#pragma unroll
        for (int nn = 0; nn < 2; ++nn) {
            const float* wp = W + (size_t)(ks * 32 + kb) * 128 + w * 32 + nn * 16 + cl16;
            unsigned uh[8], ul[8];
#pragma unroll
            for (int j = 0; j < 8; ++j) {
                float v = wp[(size_t)j * 128];
                unsigned h = rne_bf16(v);
                unsigned l = rne_bf16(v - __uint_as_float(h << 16));
                uh[j] = h; ul[j] = l;
            }
#pragma unroll
            for (int t = 0; t < 4; ++t) {
                Bh[ks][nn].u[t] = uh[2 * t] | (uh[2 * t + 1] << 16);
                Bl[ks][nn].u[t] = ul[2 * t] | (ul[2 * t + 1] << 16);
            }
        }
    }

    for (int i = tid; i < 64 * 32; i += 256) {
        int r = i >> 5, c = i & 31;
        int gr = row0 + r;
        float4 v = (gr < n) ? ((const float4*)X)[(size_t)gr * 32 + c]
                            : float4{0.f, 0.f, 0.f, 0.f};
        if (scale) {
            float4 sc = ((const float4*)scale)[c];
            float4 sh = ((const float4*)shift)[c];
            v.x = fmaxf(fmaf(v.x, sc.x, sh.x), 0.f);
            v.y = fmaxf(fmaf(v.y, sc.y, sh.y), 0.f);
            v.z = fmaxf(fmaf(v.z, sc.z, sh.z), 0.f);
            v.w = fmaxf(fmaf(v.w, sc.w, sh.w), 0.f);
        }
#pragma unroll
        for (int j = 0; j < 4; ++j) {
            float f = (&v.x)[j];
            unsigned h = rne_bf16(f);
            unsigned l = rne_bf16(f - __uint_as_float(h << 16));
            Xh[r][c * 4 + j] = (unsigned short)h;
            Xl[r][c * 4 + j] = (unsigned short)l;
        }
    }
    __syncthreads();

    f32x4 acc[4][2];
#pragma unroll
    for (int m = 0; m < 4; ++m)
#pragma unroll
        for (int nn = 0; nn < 2; ++nn) acc[m][nn] = f32x4{0.f, 0.f, 0.f, 0.f};
#pragma unroll
    for (int ks = 0; ks < 4; ++ks) {
        BF8 Ah[4], Al[4];
#pragma unroll
        for (int m = 0; m < 4; ++m) {
            const int r = m * 16 + cl16;
            const int cc = ks * 32 + kb;
            Ah[m].q = *(const uint4*)&Xh[r][cc];
            Al[m].q = *(const uint4*)&Xl[r][cc];
        }
#pragma unroll
        for (int m = 0; m < 4; ++m) {
#pragma unroll
            for (int nn = 0; nn < 2; ++nn) {
                acc[m][nn] = __builtin_amdgcn_mfma_f32_16x16x32_bf16(Ah[m].v, Bh[ks][nn].v, acc[m][nn], 0, 0, 0);
                acc[m][nn] = __builtin_amdgcn_mfma_f32_16x16x32_bf16(Ah[m].v, Bl[ks][nn].v, acc[m][nn], 0, 0, 0);
                acc[m][nn] = __builtin_amdgcn_mfma_f32_16x16x32_bf16(Al[m].v, Bh[ks][nn].v, acc[m][nn], 0, 0, 0);
            }
        }
    }

    const int rb2 = (lane >> 4) * 4;
#pragma unroll
    for (int m = 0; m < 4; ++m) {
#pragma unroll
        for (int nn = 0; nn < 2; ++nn) {
            const int col = w * 32 + nn * 16 + cl16;
#pragma unroll
            for (int r = 0; r < 4; ++r) {
                int gr = row0 + m * 16 + rb2 + r;
                if (gr < n) {
                    float val = acc[m][nn][r];
                    if (Yb) Yb[(size_t)gr * 128 + col] = (unsigned short)rne_bf16(val);
                    if (Yf) Yf[(size_t)gr * 128 + col] = val;
                }
            }
        }
    }
}

// Standalone GEMM (layer 2).
__global__ __launch_bounds__(256) void k_gemm_mfma(const float* __restrict__ X,
                                                   const float* __restrict__ W,
                                                   int n,
                                                   const float* __restrict__ scale,
                                                   const float* __restrict__ shift,
                                                   unsigned short* __restrict__ Yb,
                                                   float* __restrict__ Yf) {
    gemm_body(X, W, n, scale, shift, Yb, Yf, blockIdx.x * 64);
}

// Fat kernel: ELL-build blocks [0,nb_ell) dispatch FIRST (long pole starts
// immediately), GEMM1 blocks [nb_ell, nb_ell+nb_gm) fill in behind. Roles are
// independent (GEMM reads x,W1; ELL reads edge_index).
__global__ __launch_bounds__(256) void k_ell_gemm(const float* __restrict__ X,
                                                  const float* __restrict__ W,
                                                  int n,
                                                  unsigned short* __restrict__ Yb,
                                                  int nb_ell,
                                                  const void* __restrict__ eidx, int E,
                                                  const int* __restrict__ flag,
                                                  int* __restrict__ deg,
                                                  int* __restrict__ rec,
                                                  int2* __restrict__ ovf,
                                                  int* __restrict__ ovf_cnt, int ovf_cap) {
    const int bid = (int)blockIdx.x;
    if (bid < nb_ell) {
        ell_body(eidx, E, flag, deg, rec, ovf, ovf_cnt, ovf_cap, bid);
    } else {
        gemm_body(X, W, n, nullptr, nullptr, Yb, nullptr, (bid - nb_ell) * 64);
    }
}

// f32 GEMM (fallback path only).
__global__ __launch_bounds__(256) void k_gemm_f32(const float* __restrict__ X,
                                                  const float* __restrict__ W,
                                                  int n,
                                                  float* __restrict__ Yf) {
    __shared__ float Ws[128 * 128];
    __shared__ float Xs[32 * 128];
    const int tid = threadIdx.x;
    for (int i = tid; i < 128 * 32; i += 256)
        ((float4*)Ws)[i] = ((const float4*)W)[i];
    const int row0 = blockIdx.x * 32;
    for (int i = tid; i < 32 * 32; i += 256) {
        int r = i >> 5, c = i & 31;
        int gr = row0 + r;
        float4 v = (gr < n) ? ((const float4*)X)[(size_t)gr * 32 + c]
                            : float4{0.f, 0.f, 0.f, 0.f};
        ((float4*)Xs)[i] = v;
    }
    __syncthreads();
    const int c4 = (tid & 31) * 4;
    const int rb = tid >> 5;
    float4 acc[4];
#pragma unroll
    for (int j = 0; j < 4; ++j) acc[j] = float4{0.f, 0.f, 0.f, 0.f};
    for (int k = 0; k < 128; ++k) {
        float4 w = *(const float4*)&Ws[k * 128 + c4];
#pragma unroll
        for (int j = 0; j < 4; ++j) {
            float xv = Xs[(rb + 8 * j) * 128 + k];
            acc[j].x = fmaf(xv, w.x, acc[j].x);
            acc[j].y = fmaf(xv, w.y, acc[j].y);
            acc[j].z = fmaf(xv, w.z, acc[j].z);
            acc[j].w = fmaf(xv, w.w, acc[j].w);
        }
    }
#pragma unroll
    for (int j = 0; j < 4; ++j) {
        int r = row0 + rb + 8 * j;
        if (r < n) *(float4*)&Yf[(size_t)r * 128 + c4] = acc[j];
    }
}

// One wave per dst row (R10 structure, verbatim).
__global__ __launch_bounds__(256) void k_agg(const int* __restrict__ rec,
                                             const int* __restrict__ deg,
                                             const unsigned* __restrict__ Hb,
                                             const float* __restrict__ bias,
                                             float* __restrict__ B, int n) {
    const int d = blockIdx.x * 4 + (threadIdx.x >> 6);
    if (d >= n) return;
    const int lane = threadIdx.x & 63;
    const int cnt = __builtin_amdgcn_readfirstlane(deg[d]);
    const int cl = cnt < ELLW ? cnt : ELLW;
    const float dinv_d = rsqrtf((float)(cnt + 1));
    const float selfn = dinv_d * dinv_d;
    unsigned hu = Hb[(size_t)d * 64 + lane];
    float2 bb = ((const float2*)bias)[lane];
    float accx = fmaf(bflo(hu), selfn, bb.x);
    float accy = fmaf(bfhi(hu), selfn, bb.y);
    const int* row = rec + (size_t)d * ELLW;
    int e = 0;
    for (; e + 3 < cl; e += 4) {
        int4 ra = *(const int4*)&row[e];
        float n0 = rsqrtf((float)(deg[ra.x] + 1)) * dinv_d;
        float n1 = rsqrtf((float)(deg[ra.y] + 1)) * dinv_d;
        float n2 = rsqrtf((float)(deg[ra.z] + 1)) * dinv_d;
        float n3 = rsqrtf((float)(deg[ra.w] + 1)) * dinv_d;
        unsigned u0 = Hb[(size_t)ra.x * 64 + lane];
        unsigned u1 = Hb[(size_t)ra.y * 64 + lane];
        unsigned u2 = Hb[(size_t)ra.z * 64 + lane];
        unsigned u3 = Hb[(size_t)ra.w * 64 + lane];
        accx = fmaf(bflo(u0), n0, accx); accy = fmaf(bfhi(u0), n0, accy);
        accx = fmaf(bflo(u1), n1, accx); accy = fmaf(bfhi(u1), n1, accy);
        accx = fmaf(bflo(u2), n2, accx); accy = fmaf(bfhi(u2), n2, accy);
        accx = fmaf(bflo(u3), n3, accx); accy = fmaf(bfhi(u3), n3, accy);
    }
    for (; e < cl; ++e) {
        int r = row[e];
        float n0 = rsqrtf((float)(deg[r] + 1)) * dinv_d;
        unsigned u0 = Hb[(size_t)r * 64 + lane];
        accx = fmaf(bflo(u0), n0, accx); accy = fmaf(bfhi(u0), n0, accy);
    }
    ((float2*)(B + (size_t)d * 128))[lane] = make_float2(accx, accy);
}

// Replay overflow edges (normally zero) with f32 atomics.
__global__ __launch_bounds__(256) void k_ovf(const int2* __restrict__ ovf,
                                             const int* __restrict__ ovf_cnt,
                                             const int* __restrict__ deg,
                                             const unsigned* __restrict__ Hb,
                                             float* __restrict__ B, int ovf_cap) {
    int m = *ovf_cnt;
    if (m > ovf_cap) m = ovf_cap;
    const int lane = threadIdx.x & 63;
    for (int i = blockIdx.x * 4 + (threadIdx.x >> 6); i < m; i += gridDim.x * 4) {
        int2 sd = ovf[i];
        float nrm = rsqrtf((float)(deg[sd.x] + 1)) * rsqrtf((float)(deg[sd.y] + 1));
        unsigned u = Hb[(size_t)sd.x * 64 + lane];
        atomicAdd(&B[(size_t)sd.y * 128 + 2 * lane], bflo(u) * nrm);
        atomicAdd(&B[(size_t)sd.y * 128 + 2 * lane + 1], bfhi(u) * nrm);
    }
}

// Per-block column partials (non-atomic); grid = STATB blocks.
__global__ __launch_bounds__(256) void k_bnstats(const float* __restrict__ B, int n,
                                                 float* __restrict__ partials) {
    __shared__ float rs[256], rss[256];
    int col = threadIdx.x & 127;
    int rg = threadIdx.x >> 7;
    float s = 0.f, ss = 0.f;
    for (int r = blockIdx.x * 2 + rg; r < n; r += gridDim.x * 2) {
        float v = B[(size_t)r * 128 + col];
        s += v;
        ss = fmaf(v, v, ss);
    }
    rs[threadIdx.x] = s;
    rss[threadIdx.x] = ss;
    __syncthreads();
    if (threadIdx.x < 128) {
        partials[blockIdx.x * 256 + threadIdx.x] = rs[threadIdx.x] + rs[threadIdx.x + 128];
        partials[blockIdx.x * 256 + 128 + threadIdx.x] = rss[threadIdx.x] + rss[threadIdx.x + 128];
    }
}

// Parallel reduce of STATB partial blocks -> folded BN affine (scale, shift).
__global__ __launch_bounds__(1024) void k_bnfold(const float* __restrict__ partials,
                                                 const float* __restrict__ gamma,
                                                 const float* __restrict__ beta,
                                                 float invn, int nblk,
                                                 float* __restrict__ scale,
                                                 float* __restrict__ shift) {
    __shared__ float ls[8][128], lq[8][128];
    const int col = threadIdx.x & 127;
    const int grp = threadIdx.x >> 7;  // 0..7
    float s = 0.f, ss = 0.f;
#pragma unroll 4
    for (int b = grp; b < nblk; b += 8) {
        s += partials[b * 256 + col];
        ss += partials[b * 256 + 128 + col];
    }
    ls[grp][col] = s;
    lq[grp][col] = ss;
    __syncthreads();
    if (threadIdx.x < 128) {
        int c = threadIdx.x;
        float st = 0.f, sq = 0.f;
#pragma unroll
        for (int g = 0; g < 8; ++g) { st += ls[g][c]; sq += lq[g][c]; }
        float m = st * invn;
        float var = fmaf(-m, m, sq * invn);
        float sc = rsqrtf(var + BN_EPS) * gamma[c];
        scale[c] = sc;
        shift[c] = fmaf(-m, sc, beta[c]);
    }
}

// out = relu(x*scale + shift)
__global__ __launch_bounds__(256) void k_bnapply(const float* __restrict__ Bin,
                                                 float* __restrict__ out,
                                                 const float* __restrict__ scale,
                                                 const float* __restrict__ shift,
                                                 int n) {
    int idx = blockIdx.x * 256 + threadIdx.x;
    if (idx >= n * 32) return;
    int c4 = idx & 31;
    float4 x = ((const float4*)Bin)[idx];
    float4 sc = ((const float4*)scale)[c4];
    float4 sh = ((const float4*)shift)[c4];
    float4 o;
    o.x = fmaxf(fmaf(x.x, sc.x, sh.x), 0.f);
    o.y = fmaxf(fmaf(x.y, sc.y, sh.y), 0.f);
    o.z = fmaxf(fmaf(x.z, sc.z, sh.z), 0.f);
    o.w = fmaxf(fmaf(x.w, sc.w, sh.w), 0.f);
    ((float4*)out)[idx] = o;
}

// ---- fallback (atomic) path kernels ----
__global__ __launch_bounds__(256) void k_init_deg(int* __restrict__ deg, int n) {
    int i = blockIdx.x * 256 + threadIdx.x;
    if (i < n) deg[i] = 1;
}

__global__ __launch_bounds__(256) void k_count_deg(const void* __restrict__ eidx, int E,
                                                   const int* __restrict__ flag,
                                                   int* __restrict__ deg) {
    int e = blockIdx.x * 256 + threadIdx.x;
    if (e >= E) return;
    int d;
    if (*flag) d = (int)((const long long*)eidx)[E + e];
    else       d = ((const int*)eidx)[E + e];
    atomicAdd(&deg[d], 1);
}

__global__ __launch_bounds__(256) void k_dinv(const int* __restrict__ deg,
                                              float* __restrict__ dinv, int n) {
    int i = blockIdx.x * 256 + threadIdx.x;
    if (i < n) dinv[i] = rsqrtf((float)deg[i]);
}

__global__ __launch_bounds__(256) void k_selfloop(const float* __restrict__ H,
                                                  const float* __restrict__ dinv,
                                                  const float* __restrict__ bias,
                                                  float* __restrict__ B, int n) {
    int idx = blockIdx.x * 256 + threadIdx.x;
    if (idx >= n * 32) return;
    int r = idx >> 5, c = idx & 31;
    float s = dinv[r];
    s *= s;
    float4 h = ((const float4*)H)[idx];
    float4 bb = ((const float4*)bias)[c];
    float4 o{fmaf(h.x, s, bb.x), fmaf(h.y, s, bb.y),
             fmaf(h.z, s, bb.z), fmaf(h.w, s, bb.w)};
    ((float4*)B)[idx] = o;
}

__global__ __launch_bounds__(256) void k_edge(const void* __restrict__ eidx, int E,
                                              const int* __restrict__ flag,
                                              const float* __restrict__ dinv,
                                              const float* __restrict__ H,
                                              float* __restrict__ B) {
    int e = blockIdx.x * 8 + (threadIdx.x >> 5);
    if (e >= E) return;
    int lane = threadIdx.x & 31;
    int s, d;
    if (*flag) {
        s = (int)((const long long*)eidx)[e];
        d = (int)((const long long*)eidx)[E + e];
    } else {
        s = ((const int*)eidx)[e];
        d = ((const int*)eidx)[E + e];
    }
    float nrm = dinv[s] * dinv[d];
    float4 h = ((const float4*)(H + (size_t)s * 128))[lane];
    float* out = B + (size_t)d * 128 + lane * 4;
    atomicAdd(out + 0, h.x * nrm);
    atomicAdd(out + 1, h.y * nrm);
    atomicAdd(out + 2, h.z * nrm);
    atomicAdd(out + 3, h.w * nrm);
}

static inline char* align256(char* p) {
    return (char*)(((uintptr_t)p + 255) & ~(uintptr_t)255);
}

extern "C" void kernel_launch(void* const* d_in, const int* in_sizes, int n_in,
                              void* d_out, int out_size, void* d_ws, size_t ws_size,
                              hipStream_t stream) {
    const float* x   = (const float*)d_in[0];
    const void*  ei  = d_in[1];
    const float* W1  = (const float*)d_in[2];
    const float* b1  = (const float*)d_in[3];
    const float* g1  = (const float*)d_in[4];
    const float* be1 = (const float*)d_in[5];
    const float* W2  = (const float*)d_in[6];
    const float* b2  = (const float*)d_in[7];
    const float* g2  = (const float*)d_in[8];
    const float* be2 = (const float*)d_in[9];

    const int n = in_sizes[0] / 128;
    const int E = in_sizes[1] / 2;
    const float invn = 1.0f / (float)n;
    float* out = (float*)d_out;

    const int nb_n   = (n + 255) / 256;
    const int nb_e   = (E + 255) / 256;
    const int nb_e8  = (E + 2047) / 2048;   // ell: 8 edges/thread
    const int nb_el  = (n * 32 + 255) / 256;
    const int nb_gm  = (n + 63) / 64;
    const int nb_gf  = (n + 31) / 32;
    const int nb_edge = (E + 7) / 8;
    const int nb_agg = (n + 3) / 4;

    // ---- main (ELL) layout ----
    char* p = (char*)d_ws;
    float* B = (float*)p;                      p += (size_t)n * 128 * 4;
    unsigned short* Ab = (unsigned short*)p;   p += (size_t)n * 128 * 2;
    p = align256(p);
    int* rec = (int*)p;                        p += (size_t)n * ELLW * 4;
    int2* ovf = (int2*)p;                      p += (size_t)E * 8;
    int* deg = (int*)p;                        p += (size_t)n * 4;
    int* ovf_cnt = (int*)p;                    p += 4;
    p = align256(p);
    float* partials = (float*)p;               p += (size_t)STATB * 256 * 4;
    float* scale = (float*)p;                  p += 128 * 4;
    float* shift = (float*)p;                  p += 128 * 4;
    int* flag = (int*)p;                       p += 16;
    const bool ell_ok = (size_t)(p - (char*)d_ws) <= ws_size;

    if (ell_ok) {
        k_detect_i64<<<1, 256, 0, stream>>>((const unsigned*)ei, flag);
        hipMemsetAsync(deg, 0, (size_t)n * 4 + 4, stream);  // deg + ovf_cnt

        // ---- layer 1: ELL-build (first) fused with GEMM1 ----
        k_ell_gemm<<<nb_e8 + nb_gm, 256, 0, stream>>>(x, W1, n, Ab, nb_e8,
                                                      ei, E, flag, deg, rec,
                                                      ovf, ovf_cnt, E);
        k_agg<<<nb_agg, 256, 0, stream>>>(rec, deg, (const unsigned*)Ab, b1, B, n);
        k_ovf<<<16, 256, 0, stream>>>(ovf, ovf_cnt, deg, (const unsigned*)Ab, B, E);
        k_bnstats<<<STATB, 256, 0, stream>>>(B, n, partials);
        k_bnfold<<<1, 1024, 0, stream>>>(partials, g1, be1, invn, STATB, scale, shift);

        // ---- layer 2 (BN1+ReLU folded into GEMM staging) ----
        k_gemm_mfma<<<nb_gm, 256, 0, stream>>>(B, W2, n, scale, shift, Ab, nullptr);
        k_agg<<<nb_agg, 256, 0, stream>>>(rec, deg, (const unsigned*)Ab, b2, B, n);
        k_ovf<<<16, 256, 0, stream>>>(ovf, ovf_cnt, deg, (const unsigned*)Ab, B, E);
        k_bnstats<<<STATB, 256, 0, stream>>>(B, n, partials);
        k_bnfold<<<1, 1024, 0, stream>>>(partials, g2, be2, invn, STATB, scale, shift);
        k_bnapply<<<nb_el, 256, 0, stream>>>(B, out, scale, shift, n);
    } else {
        // ---- fallback: atomic scatter path (f32 H) ----
        char* q = (char*)d_ws;
        float* A = (float*)q;        q += (size_t)n * 128 * 4;
        float* Bf = (float*)q;       q += (size_t)n * 128 * 4;
        int* degf = (int*)q;         q += (size_t)n * 4;
        float* dinv = (float*)q;     q += (size_t)n * 4;
        q = align256(q);
        float* part = (float*)q;     q += (size_t)STATB * 256 * 4;
        float* sc = (float*)q;       q += 128 * 4;
        float* sh = (float*)q;       q += 128 * 4;
        int* flg = (int*)q;          q += 16;

        k_detect_i64<<<1, 256, 0, stream>>>((const unsigned*)ei, flg);
        k_init_deg<<<nb_n, 256, 0, stream>>>(degf, n);
        k_count_deg<<<nb_e, 256, 0, stream>>>(ei, E, flg, degf);
        k_dinv<<<nb_n, 256, 0, stream>>>(degf, dinv, n);

        k_gemm_f32<<<nb_gf, 256, 0, stream>>>(x, W1, n, A);
        k_selfloop<<<nb_el, 256, 0, stream>>>(A, dinv, b1, Bf, n);
        k_edge<<<nb_edge, 256, 0, stream>>>(ei, E, flg, dinv, A, Bf);
        k_bnstats<<<STATB, 256, 0, stream>>>(Bf, n, part);
        k_bnfold<<<1, 1024, 0, stream>>>(part, g1, be1, invn, STATB, sc, sh);
        k_bnapply<<<nb_el, 256, 0, stream>>>(Bf, Bf, sc, sh, n);

        k_gemm_f32<<<nb_gf, 256, 0, stream>>>(Bf, W2, n, A);
        k_selfloop<<<nb_el, 256, 0, stream>>>(A, dinv, b2, Bf, n);
        k_edge<<<nb_edge, 256, 0, stream>>>(ei, E, flg, dinv, A, Bf);
        k_bnstats<<<STATB, 256, 0, stream>>>(Bf, n, part);
        k_bnfold<<<1, 1024, 0, stream>>>(part, g2, be2, invn, STATB, sc, sh);
        k_bnapply<<<nb_el, 256, 0, stream>>>(Bf, out, sc, sh, n);
    }
}